// Round 4
// baseline (1684.752 us; speedup 1.0000x reference)
//
#include <hip/hip_runtime.h>
#include <hip/hip_bf16.h>

typedef __hip_bfloat16 bf16;

#define BDIM 4
#define CDIM 512
#define NHEADS 8
#define NGROUPS 4
#define GCH 128

__device__ __forceinline__ float bf2f(bf16 v) { return __bfloat162float(v); }

__device__ __forceinline__ float4 load4(const float* p) { return *reinterpret_cast<const float4*>(p); }
__device__ __forceinline__ float4 load4(const bf16* p) {
  ushort4 u = *reinterpret_cast<const ushort4*>(p);
  float4 r;
  r.x = __uint_as_float(((unsigned)u.x) << 16);
  r.y = __uint_as_float(((unsigned)u.y) << 16);
  r.z = __uint_as_float(((unsigned)u.z) << 16);
  r.w = __uint_as_float(((unsigned)u.w) << 16);
  return r;
}

__device__ __forceinline__ void stv(float* p, float v) { *p = v; }
__device__ __forceinline__ void stv(bf16* p, float v) { *p = __float2bfloat16(v); }

// out[b][o][n] = sum_c W[o][c] * in[b][c][n] + bias[o];  O=C=512, N=1024, B=4
template <typename InT, typename OutT>
__global__ __launch_bounds__(256) void conv1x1_kernel(
    const float* __restrict__ Wm, const float* __restrict__ bias,
    const InT* __restrict__ in, OutT* __restrict__ out) {
  __shared__ float Wt[16][64];  // [k][o]
  __shared__ float Xt[16][64];  // [k][n]
  const int b = blockIdx.z;
  const int o0 = blockIdx.y * 64;
  const int n0 = blockIdx.x * 64;
  const int t = threadIdx.x;
  const int tx = t & 15, ty = t >> 4;
  const int lw_o = t >> 2, lw_k = (t & 3) * 4;
  const int lx_k = t >> 4, lx_n = (t & 15) * 4;
  float acc[4][4] = {};
  for (int k0 = 0; k0 < CDIM; k0 += 16) {
    float4 wv = load4(Wm + (size_t)(o0 + lw_o) * CDIM + k0 + lw_k);
    Wt[lw_k + 0][lw_o] = wv.x;
    Wt[lw_k + 1][lw_o] = wv.y;
    Wt[lw_k + 2][lw_o] = wv.z;
    Wt[lw_k + 3][lw_o] = wv.w;
    float4 xv = load4(in + ((size_t)b * CDIM + k0 + lx_k) * 1024 + n0 + lx_n);
    *reinterpret_cast<float4*>(&Xt[lx_k][lx_n]) = xv;
    __syncthreads();
#pragma unroll
    for (int k = 0; k < 16; k++) {
      const float4 a = *reinterpret_cast<const float4*>(&Wt[k][ty * 4]);
      const float4 x = *reinterpret_cast<const float4*>(&Xt[k][tx * 4]);
      const float av[4] = {a.x, a.y, a.z, a.w};
      const float xv2[4] = {x.x, x.y, x.z, x.w};
#pragma unroll
      for (int j = 0; j < 4; j++)
#pragma unroll
        for (int i = 0; i < 4; i++) acc[j][i] += av[j] * xv2[i];
    }
    __syncthreads();
  }
#pragma unroll
  for (int j = 0; j < 4; j++) {
    const int o = o0 + ty * 4 + j;
    const float bv = bias[o];
#pragma unroll
    for (int i = 0; i < 4; i++)
      stv(out + ((size_t)b * CDIM + o) * 1024 + n0 + tx * 4 + i, acc[j][i] + bv);
  }
}

// depthwise 5x5 conv + LayerNorm(128) + exact GELU + 1x1(128->2) + tanh -> pos
__global__ __launch_bounds__(128) void offset_kernel(
    const bf16* __restrict__ q, const float* __restrict__ dw_w,
    const float* __restrict__ dw_b, const float* __restrict__ ln_g,
    const float* __restrict__ ln_b, const float* __restrict__ off_w,
    float* __restrict__ pos, float* __restrict__ out_pos, float* __restrict__ out_ref) {
  const int bg = blockIdx.x;  // 0..15
  const int h = blockIdx.y;   // 0..31
  const int c = threadIdx.x;  // 0..127 (channel)
  const int b = bg >> 2, g = bg & 3;
  const bf16* qp = q + ((size_t)b * CDIM + g * GCH + c) * 1024;
  float wgt[25];
#pragma unroll
  for (int i = 0; i < 25; i++) wgt[i] = dw_w[c * 25 + i];
  const float cbias = dw_b[c];
  const float gam = ln_g[c], bet = ln_b[c];
  const float ow0 = off_w[c], ow1 = off_w[GCH + c];
  __shared__ float red[8];
  for (int w = 0; w < 32; w++) {
    float s = cbias;
#pragma unroll
    for (int ky = 0; ky < 5; ky++) {
      const int y = h + ky - 2;
      if (y < 0 || y >= 32) continue;
#pragma unroll
      for (int kx = 0; kx < 5; kx++) {
        const int x = w + kx - 2;
        if (x < 0 || x >= 32) continue;
        s += wgt[ky * 5 + kx] * bf2f(qp[y * 32 + x]);
      }
    }
    float ssum = s, ssq = s * s;
#pragma unroll
    for (int o = 1; o < 64; o <<= 1) {
      ssum += __shfl_xor(ssum, o);
      ssq += __shfl_xor(ssq, o);
    }
    if ((c & 63) == 0) { red[c >> 6] = ssum; red[2 + (c >> 6)] = ssq; }
    __syncthreads();
    const float mu = (red[0] + red[1]) * (1.0f / 128.0f);
    const float var = (red[2] + red[3]) * (1.0f / 128.0f) - mu * mu;
    const float xn = (s - mu) * rsqrtf(var + 1e-5f) * gam + bet;
    const float ge = 0.5f * xn * (1.0f + erff(xn * 0.70710678118654752f));
    float p0 = ow0 * ge, p1 = ow1 * ge;
#pragma unroll
    for (int o = 1; o < 64; o <<= 1) {
      p0 += __shfl_xor(p0, o);
      p1 += __shfl_xor(p1, o);
    }
    if ((c & 63) == 0) { red[4 + (c >> 6)] = p0; red[6 + (c >> 6)] = p1; }
    __syncthreads();
    if (c == 0) {
      const float oy = tanhf(red[4] + red[5]) * 0.0625f;  // (1/32)*2
      const float ox = tanhf(red[6] + red[7]) * 0.0625f;
      const float ry = ((float)h + 0.5f) * (2.0f / 32.0f) - 1.0f;
      const float rx = ((float)w + 0.5f) * (2.0f / 32.0f) - 1.0f;
      const float py = oy + ry, px = ox + rx;
      const size_t idx = (size_t)bg * 1024 + h * 32 + w;
      pos[idx * 2] = py;
      pos[idx * 2 + 1] = px;
      out_pos[idx * 2] = py;
      out_pos[idx * 2 + 1] = px;
      out_ref[idx * 2] = ry;
      out_ref[idx * 2 + 1] = rx;
    }
    __syncthreads();
  }
}

// bilinear grid-sample of x at pos -> xs [16][128][1024]
__global__ __launch_bounds__(256) void sample_kernel(
    const float* __restrict__ x, const float* __restrict__ pos, bf16* __restrict__ xs) {
  const int bg = blockIdx.x, c = blockIdx.y;
  const int b = bg >> 2, g = bg & 3;
  __shared__ float plane[1024];
  const float* xp = x + ((size_t)b * CDIM + g * GCH + c) * 1024;
  for (int i = threadIdx.x; i < 1024; i += 256) plane[i] = xp[i];
  __syncthreads();
  for (int s = threadIdx.x; s < 1024; s += 256) {
    const float py = pos[((size_t)bg * 1024 + s) * 2];
    const float px = pos[((size_t)bg * 1024 + s) * 2 + 1];
    const float gx = (px + 1.0f) * 15.5f;  // align_corners=True, W=32
    const float gy = (py + 1.0f) * 15.5f;
    const float x0f = floorf(gx), y0f = floorf(gy);
    const float wx = gx - x0f, wy = gy - y0f;
    const int ix = (int)x0f, iy = (int)y0f;
    float r = 0.0f;
    const bool vx0 = (ix >= 0) & (ix <= 31), vx1 = (ix + 1 >= 0) & (ix + 1 <= 31);
    const bool vy0 = (iy >= 0) & (iy <= 31), vy1 = (iy + 1 >= 0) & (iy + 1 <= 31);
    if (vy0 && vx0) r += plane[iy * 32 + ix] * (1.0f - wx) * (1.0f - wy);
    if (vy0 && vx1) r += plane[iy * 32 + ix + 1] * wx * (1.0f - wy);
    if (vy1 && vx0) r += plane[(iy + 1) * 32 + ix] * (1.0f - wx) * wy;
    if (vy1 && vx1) r += plane[(iy + 1) * 32 + ix + 1] * wx * wy;
    xs[((size_t)bg * GCH + c) * 1024 + s] = __float2bfloat16(r);
  }
}

// fused attention: logits = q.k*scale + rpe_bilinear(disp), online softmax, PV
__global__ __launch_bounds__(256) void attn_kernel(
    const bf16* __restrict__ q, const bf16* __restrict__ kk,
    const bf16* __restrict__ vv, const float* __restrict__ pos,
    const float* __restrict__ rpe, bf16* __restrict__ ao) {
  __shared__ float q_s[64][33];    // [c][m]
  __shared__ float k_s[64][68];    // [c][n]
  __shared__ float v_s[64][68];    // [n][c]
  __shared__ float p_s[32][68];    // [m][n]
  __shared__ float rpe_s[63 * 63];
  const int bh = blockIdx.y;       // 0..31
  const int m0 = blockIdx.x * 32;  // query tile
  const int b = bh >> 3, h = bh & 7;
  const int g = h >> 1;
  const int bg = b * 4 + g;
  const int t = threadIdx.x;
  const size_t hbase = ((size_t)b * CDIM + h * 64) * 1024;
  for (int i = t; i < 63 * 63; i += 256) rpe_s[i] = rpe[h * 3969 + i];
  for (int i = t * 4; i < 64 * 32; i += 1024) {
    const int ch = i >> 5, col = i & 31;
    const float4 qv = load4(q + hbase + (size_t)ch * 1024 + m0 + col);
    q_s[ch][col] = qv.x; q_s[ch][col + 1] = qv.y;
    q_s[ch][col + 2] = qv.z; q_s[ch][col + 3] = qv.w;
  }
  const int mi = t >> 3;        // owned query row 0..31
  const int n8 = (t & 7) * 8;   // owned key range (QK) / channel block (PV)
  const int m = m0 + mi;
  const float qy = ((float)(m >> 5) + 0.5f) * (2.0f / 32.0f) - 1.0f;
  const float qx = ((float)(m & 31) + 0.5f) * (2.0f / 32.0f) - 1.0f;
  float row_max = -1e30f, row_sum = 0.0f;
  float oacc[8] = {};
  const float* posb = pos + (size_t)bg * 2048;
  for (int n0 = 0; n0 < 1024; n0 += 64) {
    __syncthreads();
    for (int i = t * 4; i < 64 * 64; i += 1024) {
      const int cc = i >> 6, nn = i & 63;
      const float4 kv = load4(kk + hbase + (size_t)cc * 1024 + n0 + nn);
      const float4 v4 = load4(vv + hbase + (size_t)cc * 1024 + n0 + nn);
      k_s[cc][nn] = kv.x; k_s[cc][nn + 1] = kv.y; k_s[cc][nn + 2] = kv.z; k_s[cc][nn + 3] = kv.w;
      v_s[nn][cc] = v4.x; v_s[nn + 1][cc] = v4.y; v_s[nn + 2][cc] = v4.z; v_s[nn + 3][cc] = v4.w;
    }
    __syncthreads();
    float sv[8];
#pragma unroll
    for (int j = 0; j < 8; j++) sv[j] = 0.0f;
    for (int c = 0; c < 64; c++) {
      const float qvv = q_s[c][mi];
      const float4 k0v = *reinterpret_cast<const float4*>(&k_s[c][n8]);
      const float4 k1v = *reinterpret_cast<const float4*>(&k_s[c][n8 + 4]);
      sv[0] += qvv * k0v.x; sv[1] += qvv * k0v.y; sv[2] += qvv * k0v.z; sv[3] += qvv * k0v.w;
      sv[4] += qvv * k1v.x; sv[5] += qvv * k1v.y; sv[6] += qvv * k1v.z; sv[7] += qvv * k1v.w;
    }
#pragma unroll
    for (int j = 0; j < 8; j++) {
      const int n = n0 + n8 + j;
      const float dy = (qy - posb[n * 2]) * 0.5f;
      const float dx = (qx - posb[n * 2 + 1]) * 0.5f;
      const float gxc = (dx + 1.0f) * 31.0f;  // align_corners=True, (63-1)/2
      const float gyc = (dy + 1.0f) * 31.0f;
      const float x0f = floorf(gxc), y0f = floorf(gyc);
      const float wx = gxc - x0f, wy = gyc - y0f;
      const int ix = (int)x0f, iy = (int)y0f;
      float biasv = 0.0f;
      const bool vx0 = (ix >= 0) & (ix <= 62), vx1 = (ix + 1 >= 0) & (ix + 1 <= 62);
      const bool vy0 = (iy >= 0) & (iy <= 62), vy1 = (iy + 1 >= 0) & (iy + 1 <= 62);
      if (vy0 && vx0) biasv += rpe_s[iy * 63 + ix] * (1.0f - wx) * (1.0f - wy);
      if (vy0 && vx1) biasv += rpe_s[iy * 63 + ix + 1] * wx * (1.0f - wy);
      if (vy1 && vx0) biasv += rpe_s[(iy + 1) * 63 + ix] * (1.0f - wx) * wy;
      if (vy1 && vx1) biasv += rpe_s[(iy + 1) * 63 + ix + 1] * wx * wy;
      sv[j] = sv[j] * 0.125f + biasv;
    }
    float tmax = sv[0];
#pragma unroll
    for (int j = 1; j < 8; j++) tmax = fmaxf(tmax, sv[j]);
#pragma unroll
    for (int o = 1; o < 8; o <<= 1) tmax = fmaxf(tmax, __shfl_xor(tmax, o));
    const float nmax = fmaxf(row_max, tmax);
    const float corr = __expf(row_max - nmax);
    float lsum = 0.0f;
#pragma unroll
    for (int j = 0; j < 8; j++) {
      const float p = __expf(sv[j] - nmax);
      p_s[mi][n8 + j] = p;
      lsum += p;
    }
#pragma unroll
    for (int o = 1; o < 8; o <<= 1) lsum += __shfl_xor(lsum, o);
    row_sum = row_sum * corr + lsum;
    row_max = nmax;
#pragma unroll
    for (int j = 0; j < 8; j++) oacc[j] *= corr;
    __syncthreads();
    for (int n = 0; n < 64; n++) {
      const float pv = p_s[mi][n];
      const float4 v0 = *reinterpret_cast<const float4*>(&v_s[n][n8]);
      const float4 v1 = *reinterpret_cast<const float4*>(&v_s[n][n8 + 4]);
      oacc[0] += pv * v0.x; oacc[1] += pv * v0.y; oacc[2] += pv * v0.z; oacc[3] += pv * v0.w;
      oacc[4] += pv * v1.x; oacc[5] += pv * v1.y; oacc[6] += pv * v1.z; oacc[7] += pv * v1.w;
    }
  }
  const float inv = 1.0f / row_sum;
#pragma unroll
  for (int j = 0; j < 8; j++)
    ao[hbase + (size_t)(n8 + j) * 1024 + m] = __float2bfloat16(oacc[j] * inv);
}

extern "C" void kernel_launch(void* const* d_in, const int* in_sizes, int n_in,
                              void* d_out, int out_size, void* d_ws, size_t ws_size,
                              hipStream_t stream) {
  const float* x    = (const float*)d_in[0];
  const float* w_q  = (const float*)d_in[1];
  const float* b_q  = (const float*)d_in[2];
  const float* w_k  = (const float*)d_in[3];
  const float* b_k  = (const float*)d_in[4];
  const float* w_v  = (const float*)d_in[5];
  const float* b_v  = (const float*)d_in[6];
  const float* w_o  = (const float*)d_in[7];
  const float* b_o  = (const float*)d_in[8];
  const float* dw_w = (const float*)d_in[9];
  const float* dw_b = (const float*)d_in[10];
  const float* ln_g = (const float*)d_in[11];
  const float* ln_b = (const float*)d_in[12];
  const float* off_w= (const float*)d_in[13];
  const float* rpe  = (const float*)d_in[14];

  // Outputs are FLOAT32 (reference returns f32 arrays).
  float* out_y   = (float*)d_out;            // [4,512,32,32]   (2097152 f32)
  float* out_pos = out_y + 2097152;          // [4,4,32,32,2]   (32768 f32)
  float* out_ref = out_pos + 32768;          // [4,4,32,32,2]   (32768 f32)

  // workspace: pos (f32, 128KB) first, then bf16 intermediates (4MB each).
  float* pos_ws = (float*)d_ws;              // 32768 floats
  bf16*  q_ws   = (bf16*)(pos_ws + 32768);   // 2097152 bf16
  bf16*  xs_ws  = q_ws + 2097152;            // 2097152 bf16 (reused as ao)
  bf16*  k_ws   = xs_ws + 2097152;
  bf16*  v_ws   = k_ws + 2097152;
  bf16*  ao_ws  = xs_ws;                     // xs dead after k/v convs

  conv1x1_kernel<float, bf16><<<dim3(16, 8, 4), 256, 0, stream>>>(w_q, b_q, x, q_ws);
  offset_kernel<<<dim3(16, 32), 128, 0, stream>>>(q_ws, dw_w, dw_b, ln_g, ln_b, off_w,
                                                  pos_ws, out_pos, out_ref);
  sample_kernel<<<dim3(16, 128), 256, 0, stream>>>(x, pos_ws, xs_ws);
  conv1x1_kernel<bf16, bf16><<<dim3(16, 8, 4), 256, 0, stream>>>(w_k, b_k, xs_ws, k_ws);
  conv1x1_kernel<bf16, bf16><<<dim3(16, 8, 4), 256, 0, stream>>>(w_v, b_v, xs_ws, v_ws);
  attn_kernel<<<dim3(32, 32), 256, 0, stream>>>(q_ws, k_ws, v_ws, pos_ws, rpe, ao_ws);
  conv1x1_kernel<bf16, float><<<dim3(16, 8, 4), 256, 0, stream>>>(w_o, b_o, ao_ws, out_y);
}

// Round 5
// 532.745 us; speedup vs baseline: 3.1624x; 3.1624x over previous
//
#include <hip/hip_runtime.h>
#include <hip/hip_bf16.h>

typedef __hip_bfloat16 bf16;

#define BDIM 4
#define CDIM 512
#define NHEADS 8
#define NGROUPS 4
#define GCH 128

__device__ __forceinline__ float bf2f(bf16 v) { return __bfloat162float(v); }

__device__ __forceinline__ float4 load4(const float* p) { return *reinterpret_cast<const float4*>(p); }
__device__ __forceinline__ float4 load4(const bf16* p) {
  ushort4 u = *reinterpret_cast<const ushort4*>(p);
  float4 r;
  r.x = __uint_as_float(((unsigned)u.x) << 16);
  r.y = __uint_as_float(((unsigned)u.y) << 16);
  r.z = __uint_as_float(((unsigned)u.z) << 16);
  r.w = __uint_as_float(((unsigned)u.w) << 16);
  return r;
}

__device__ __forceinline__ void stv(float* p, float v) { *p = v; }
__device__ __forceinline__ void stv(bf16* p, float v) { *p = __float2bfloat16(v); }

// out[b][o][n] = sum_c W[o][c] * in[b][c][n] + bias[o];  O=C=512, N=1024, B=4
template <typename InT, typename OutT>
__global__ __launch_bounds__(256) void conv1x1_kernel(
    const float* __restrict__ Wm, const float* __restrict__ bias,
    const InT* __restrict__ in, OutT* __restrict__ out) {
  __shared__ float Wt[16][64];  // [k][o]
  __shared__ float Xt[16][64];  // [k][n]
  const int b = blockIdx.z;
  const int o0 = blockIdx.y * 64;
  const int n0 = blockIdx.x * 64;
  const int t = threadIdx.x;
  const int tx = t & 15, ty = t >> 4;
  const int lw_o = t >> 2, lw_k = (t & 3) * 4;
  const int lx_k = t >> 4, lx_n = (t & 15) * 4;
  float acc[4][4] = {};
  for (int k0 = 0; k0 < CDIM; k0 += 16) {
    float4 wv = load4(Wm + (size_t)(o0 + lw_o) * CDIM + k0 + lw_k);
    Wt[lw_k + 0][lw_o] = wv.x;
    Wt[lw_k + 1][lw_o] = wv.y;
    Wt[lw_k + 2][lw_o] = wv.z;
    Wt[lw_k + 3][lw_o] = wv.w;
    float4 xv = load4(in + ((size_t)b * CDIM + k0 + lx_k) * 1024 + n0 + lx_n);
    *reinterpret_cast<float4*>(&Xt[lx_k][lx_n]) = xv;
    __syncthreads();
#pragma unroll
    for (int k = 0; k < 16; k++) {
      const float4 a = *reinterpret_cast<const float4*>(&Wt[k][ty * 4]);
      const float4 x = *reinterpret_cast<const float4*>(&Xt[k][tx * 4]);
      const float av[4] = {a.x, a.y, a.z, a.w};
      const float xv2[4] = {x.x, x.y, x.z, x.w};
#pragma unroll
      for (int j = 0; j < 4; j++)
#pragma unroll
        for (int i = 0; i < 4; i++) acc[j][i] += av[j] * xv2[i];
    }
    __syncthreads();
  }
#pragma unroll
  for (int j = 0; j < 4; j++) {
    const int o = o0 + ty * 4 + j;
    const float bv = bias[o];
#pragma unroll
    for (int i = 0; i < 4; i++)
      stv(out + ((size_t)b * CDIM + o) * 1024 + n0 + tx * 4 + i, acc[j][i] + bv);
  }
}

// depthwise 5x5 conv + LayerNorm(128) + exact GELU + 1x1(128->2) + tanh -> pos
__global__ __launch_bounds__(128) void offset_kernel(
    const bf16* __restrict__ q, const float* __restrict__ dw_w,
    const float* __restrict__ dw_b, const float* __restrict__ ln_g,
    const float* __restrict__ ln_b, const float* __restrict__ off_w,
    float* __restrict__ pos, float* __restrict__ out_pos, float* __restrict__ out_ref) {
  const int bg = blockIdx.x;  // 0..15
  const int h = blockIdx.y;   // 0..31
  const int c = threadIdx.x;  // 0..127 (channel)
  const int b = bg >> 2, g = bg & 3;
  const bf16* qp = q + ((size_t)b * CDIM + g * GCH + c) * 1024;
  float wgt[25];
#pragma unroll
  for (int i = 0; i < 25; i++) wgt[i] = dw_w[c * 25 + i];
  const float cbias = dw_b[c];
  const float gam = ln_g[c], bet = ln_b[c];
  const float ow0 = off_w[c], ow1 = off_w[GCH + c];
  __shared__ float red[8];
  for (int w = 0; w < 32; w++) {
    float s = cbias;
#pragma unroll
    for (int ky = 0; ky < 5; ky++) {
      const int y = h + ky - 2;
      if (y < 0 || y >= 32) continue;
#pragma unroll
      for (int kx = 0; kx < 5; kx++) {
        const int x = w + kx - 2;
        if (x < 0 || x >= 32) continue;
        s += wgt[ky * 5 + kx] * bf2f(qp[y * 32 + x]);
      }
    }
    float ssum = s, ssq = s * s;
#pragma unroll
    for (int o = 1; o < 64; o <<= 1) {
      ssum += __shfl_xor(ssum, o);
      ssq += __shfl_xor(ssq, o);
    }
    if ((c & 63) == 0) { red[c >> 6] = ssum; red[2 + (c >> 6)] = ssq; }
    __syncthreads();
    const float mu = (red[0] + red[1]) * (1.0f / 128.0f);
    const float var = (red[2] + red[3]) * (1.0f / 128.0f) - mu * mu;
    const float xn = (s - mu) * rsqrtf(var + 1e-5f) * gam + bet;
    const float ge = 0.5f * xn * (1.0f + erff(xn * 0.70710678118654752f));
    float p0 = ow0 * ge, p1 = ow1 * ge;
#pragma unroll
    for (int o = 1; o < 64; o <<= 1) {
      p0 += __shfl_xor(p0, o);
      p1 += __shfl_xor(p1, o);
    }
    if ((c & 63) == 0) { red[4 + (c >> 6)] = p0; red[6 + (c >> 6)] = p1; }
    __syncthreads();
    if (c == 0) {
      const float oy = tanhf(red[4] + red[5]) * 0.0625f;  // (1/32)*2
      const float ox = tanhf(red[6] + red[7]) * 0.0625f;
      const float ry = ((float)h + 0.5f) * (2.0f / 32.0f) - 1.0f;
      const float rx = ((float)w + 0.5f) * (2.0f / 32.0f) - 1.0f;
      const float py = oy + ry, px = ox + rx;
      const size_t idx = (size_t)bg * 1024 + h * 32 + w;
      pos[idx * 2] = py;
      pos[idx * 2 + 1] = px;
      out_pos[idx * 2] = py;
      out_pos[idx * 2 + 1] = px;
      out_ref[idx * 2] = ry;
      out_ref[idx * 2 + 1] = rx;
    }
    __syncthreads();
  }
}

// bilinear grid-sample of x at pos -> xs [16][128][1024]
__global__ __launch_bounds__(256) void sample_kernel(
    const float* __restrict__ x, const float* __restrict__ pos, bf16* __restrict__ xs) {
  const int bg = blockIdx.x, c = blockIdx.y;
  const int b = bg >> 2, g = bg & 3;
  __shared__ float plane[1024];
  const float* xp = x + ((size_t)b * CDIM + g * GCH + c) * 1024;
  for (int i = threadIdx.x; i < 1024; i += 256) plane[i] = xp[i];
  __syncthreads();
  for (int s = threadIdx.x; s < 1024; s += 256) {
    const float py = pos[((size_t)bg * 1024 + s) * 2];
    const float px = pos[((size_t)bg * 1024 + s) * 2 + 1];
    const float gx = (px + 1.0f) * 15.5f;  // align_corners=True, W=32
    const float gy = (py + 1.0f) * 15.5f;
    const float x0f = floorf(gx), y0f = floorf(gy);
    const float wx = gx - x0f, wy = gy - y0f;
    const int ix = (int)x0f, iy = (int)y0f;
    float r = 0.0f;
    const bool vx0 = (ix >= 0) & (ix <= 31), vx1 = (ix + 1 >= 0) & (ix + 1 <= 31);
    const bool vy0 = (iy >= 0) & (iy <= 31), vy1 = (iy + 1 >= 0) & (iy + 1 <= 31);
    if (vy0 && vx0) r += plane[iy * 32 + ix] * (1.0f - wx) * (1.0f - wy);
    if (vy0 && vx1) r += plane[iy * 32 + ix + 1] * wx * (1.0f - wy);
    if (vy1 && vx0) r += plane[(iy + 1) * 32 + ix] * (1.0f - wx) * wy;
    if (vy1 && vx1) r += plane[(iy + 1) * 32 + ix + 1] * wx * wy;
    xs[((size_t)bg * GCH + c) * 1024 + s] = __float2bfloat16(r);
  }
}

// fused attention: logits = q.k*scale + rpe_bilinear(disp), online softmax, PV
// Phase-split per K-tile to keep register pressure low (round-4 version spilled:
// VGPR=256, 2.5 GB scratch writes/dispatch):
//   A: bias(m,n) -> p_s   (2048 independent bilinear lookups, tiny live state)
//   B: QK dot (+bias from p_s), online softmax, p -> p_s
//   C: PV accumulate
__global__ __launch_bounds__(256) void attn_kernel(
    const bf16* __restrict__ q, const bf16* __restrict__ kk,
    const bf16* __restrict__ vv, const float* __restrict__ pos,
    const float* __restrict__ rpe, bf16* __restrict__ ao) {
  __shared__ float q_s[64][33];    // [c][m]
  __shared__ float k_s[64][68];    // [c][n]   (reused as output staging)
  __shared__ float v_s[64][68];    // [n][c]
  __shared__ float p_s[32][68];    // [m][n]
  __shared__ float rpe_s[63 * 63];
  const int bh = blockIdx.y;       // 0..31
  const int m0 = blockIdx.x * 32;  // query tile
  const int b = bh >> 3, h = bh & 7;
  const int g = h >> 1;
  const int bg = b * 4 + g;
  const int t = threadIdx.x;
  const size_t hbase = ((size_t)b * CDIM + h * 64) * 1024;
  for (int i = t; i < 63 * 63; i += 256) rpe_s[i] = rpe[h * 3969 + i];
  for (int i = t * 4; i < 64 * 32; i += 1024) {
    const int ch = i >> 5, col = i & 31;
    const float4 qv = load4(q + hbase + (size_t)ch * 1024 + m0 + col);
    q_s[ch][col] = qv.x; q_s[ch][col + 1] = qv.y;
    q_s[ch][col + 2] = qv.z; q_s[ch][col + 3] = qv.w;
  }
  const int mi = t >> 3;        // owned query row 0..31
  const int n8 = (t & 7) * 8;   // owned key range (QK) / channel block (PV)
  float row_max = -1e30f, row_sum = 0.0f;
  float oacc[8] = {};
  const float* posb = pos + (size_t)bg * 2048;
  for (int n0 = 0; n0 < 1024; n0 += 64) {
    __syncthreads();
    for (int i = t * 4; i < 64 * 64; i += 1024) {
      const int cc = i >> 6, nn = i & 63;
      const float4 kv = load4(kk + hbase + (size_t)cc * 1024 + n0 + nn);
      const float4 v4 = load4(vv + hbase + (size_t)cc * 1024 + n0 + nn);
      k_s[cc][nn] = kv.x; k_s[cc][nn + 1] = kv.y; k_s[cc][nn + 2] = kv.z; k_s[cc][nn + 3] = kv.w;
      v_s[nn][cc] = v4.x; v_s[nn + 1][cc] = v4.y; v_s[nn + 2][cc] = v4.z; v_s[nn + 3][cc] = v4.w;
    }
    __syncthreads();
    // ---- Phase A: rpe bias for this (32 x 64) tile -> p_s ----
#pragma unroll 2
    for (int i = t; i < 32 * 64; i += 256) {
      const int am = m0 + (i >> 6);
      const int an = n0 + (i & 63);
      const float aqy = ((float)(am >> 5) + 0.5f) * (2.0f / 32.0f) - 1.0f;
      const float aqx = ((float)(am & 31) + 0.5f) * (2.0f / 32.0f) - 1.0f;
      const float dy = (aqy - posb[an * 2]) * 0.5f;
      const float dx = (aqx - posb[an * 2 + 1]) * 0.5f;
      const float gxc = (dx + 1.0f) * 31.0f;  // align_corners=True, (63-1)/2
      const float gyc = (dy + 1.0f) * 31.0f;
      const float x0f = floorf(gxc), y0f = floorf(gyc);
      const float wx = gxc - x0f, wy = gyc - y0f;
      const int ix = (int)x0f, iy = (int)y0f;
      float biasv = 0.0f;
      const bool vx0 = (ix >= 0) & (ix <= 62), vx1 = (ix + 1 >= 0) & (ix + 1 <= 62);
      const bool vy0 = (iy >= 0) & (iy <= 62), vy1 = (iy + 1 >= 0) & (iy + 1 <= 62);
      if (vy0 && vx0) biasv += rpe_s[iy * 63 + ix] * (1.0f - wx) * (1.0f - wy);
      if (vy0 && vx1) biasv += rpe_s[iy * 63 + ix + 1] * wx * (1.0f - wy);
      if (vy1 && vx0) biasv += rpe_s[(iy + 1) * 63 + ix] * (1.0f - wx) * wy;
      if (vy1 && vx1) biasv += rpe_s[(iy + 1) * 63 + ix + 1] * wx * wy;
      p_s[i >> 6][i & 63] = biasv;
    }
    __syncthreads();
    // ---- Phase B: QK dot + bias, online softmax ----
    float sv[8];
#pragma unroll
    for (int j = 0; j < 8; j++) sv[j] = 0.0f;
#pragma unroll 4
    for (int c = 0; c < 64; c++) {
      const float qvv = q_s[c][mi];
      const float4 k0v = *reinterpret_cast<const float4*>(&k_s[c][n8]);
      const float4 k1v = *reinterpret_cast<const float4*>(&k_s[c][n8 + 4]);
      sv[0] += qvv * k0v.x; sv[1] += qvv * k0v.y; sv[2] += qvv * k0v.z; sv[3] += qvv * k0v.w;
      sv[4] += qvv * k1v.x; sv[5] += qvv * k1v.y; sv[6] += qvv * k1v.z; sv[7] += qvv * k1v.w;
    }
#pragma unroll
    for (int j = 0; j < 8; j++) sv[j] = sv[j] * 0.125f + p_s[mi][n8 + j];
    float tmax = sv[0];
#pragma unroll
    for (int j = 1; j < 8; j++) tmax = fmaxf(tmax, sv[j]);
#pragma unroll
    for (int o = 1; o < 8; o <<= 1) tmax = fmaxf(tmax, __shfl_xor(tmax, o));
    const float nmax = fmaxf(row_max, tmax);
    const float corr = __expf(row_max - nmax);
    float lsum = 0.0f;
#pragma unroll
    for (int j = 0; j < 8; j++) {
      const float p = __expf(sv[j] - nmax);
      p_s[mi][n8 + j] = p;
      lsum += p;
    }
#pragma unroll
    for (int o = 1; o < 8; o <<= 1) lsum += __shfl_xor(lsum, o);
    row_sum = row_sum * corr + lsum;
    row_max = nmax;
#pragma unroll
    for (int j = 0; j < 8; j++) oacc[j] *= corr;
    __syncthreads();
    // ---- Phase C: PV accumulate ----
#pragma unroll 4
    for (int n = 0; n < 64; n++) {
      const float pv = p_s[mi][n];
      const float4 v0 = *reinterpret_cast<const float4*>(&v_s[n][n8]);
      const float4 v1 = *reinterpret_cast<const float4*>(&v_s[n][n8 + 4]);
      oacc[0] += pv * v0.x; oacc[1] += pv * v0.y; oacc[2] += pv * v0.z; oacc[3] += pv * v0.w;
      oacc[4] += pv * v1.x; oacc[5] += pv * v1.y; oacc[6] += pv * v1.z; oacc[7] += pv * v1.w;
    }
  }
  // ---- epilogue: stage through LDS (reuse k_s) for coalesced bf16 stores ----
  __syncthreads();
  const float inv = 1.0f / row_sum;
#pragma unroll
  for (int j = 0; j < 8; j++) k_s[n8 + j][mi] = oacc[j] * inv;
  __syncthreads();
#pragma unroll
  for (int i = t; i < 512; i += 256) {
    const int c = i >> 3, m4 = (i & 7) * 4;
    const float4 ov = *reinterpret_cast<const float4*>(&k_s[c][m4]);
    ushort4 u;
    u.x = __hip_bfloat16_raw(__float2bfloat16(ov.x)).x;
    u.y = __hip_bfloat16_raw(__float2bfloat16(ov.y)).x;
    u.z = __hip_bfloat16_raw(__float2bfloat16(ov.z)).x;
    u.w = __hip_bfloat16_raw(__float2bfloat16(ov.w)).x;
    *reinterpret_cast<ushort4*>(ao + hbase + (size_t)c * 1024 + m0 + m4) = u;
  }
}

extern "C" void kernel_launch(void* const* d_in, const int* in_sizes, int n_in,
                              void* d_out, int out_size, void* d_ws, size_t ws_size,
                              hipStream_t stream) {
  const float* x    = (const float*)d_in[0];
  const float* w_q  = (const float*)d_in[1];
  const float* b_q  = (const float*)d_in[2];
  const float* w_k  = (const float*)d_in[3];
  const float* b_k  = (const float*)d_in[4];
  const float* w_v  = (const float*)d_in[5];
  const float* b_v  = (const float*)d_in[6];
  const float* w_o  = (const float*)d_in[7];
  const float* b_o  = (const float*)d_in[8];
  const float* dw_w = (const float*)d_in[9];
  const float* dw_b = (const float*)d_in[10];
  const float* ln_g = (const float*)d_in[11];
  const float* ln_b = (const float*)d_in[12];
  const float* off_w= (const float*)d_in[13];
  const float* rpe  = (const float*)d_in[14];

  // Outputs are FLOAT32 (reference returns f32 arrays).
  float* out_y   = (float*)d_out;            // [4,512,32,32]   (2097152 f32)
  float* out_pos = out_y + 2097152;          // [4,4,32,32,2]   (32768 f32)
  float* out_ref = out_pos + 32768;          // [4,4,32,32,2]   (32768 f32)

  // workspace: pos (f32, 128KB) first, then bf16 intermediates (4MB each).
  float* pos_ws = (float*)d_ws;              // 32768 floats
  bf16*  q_ws   = (bf16*)(pos_ws + 32768);   // 2097152 bf16
  bf16*  xs_ws  = q_ws + 2097152;            // 2097152 bf16 (reused as ao)
  bf16*  k_ws   = xs_ws + 2097152;
  bf16*  v_ws   = k_ws + 2097152;
  bf16*  ao_ws  = xs_ws;                     // xs dead after k/v convs

  conv1x1_kernel<float, bf16><<<dim3(16, 8, 4), 256, 0, stream>>>(w_q, b_q, x, q_ws);
  offset_kernel<<<dim3(16, 32), 128, 0, stream>>>(q_ws, dw_w, dw_b, ln_g, ln_b, off_w,
                                                  pos_ws, out_pos, out_ref);
  sample_kernel<<<dim3(16, 128), 256, 0, stream>>>(x, pos_ws, xs_ws);
  conv1x1_kernel<bf16, bf16><<<dim3(16, 8, 4), 256, 0, stream>>>(w_k, b_k, xs_ws, k_ws);
  conv1x1_kernel<bf16, bf16><<<dim3(16, 8, 4), 256, 0, stream>>>(w_v, b_v, xs_ws, v_ws);
  attn_kernel<<<dim3(32, 32), 256, 0, stream>>>(q_ws, k_ws, v_ws, pos_ws, rpe, ao_ws);
  conv1x1_kernel<bf16, float><<<dim3(16, 8, 4), 256, 0, stream>>>(w_o, b_o, ao_ws, out_y);
}

// Round 6
// 434.392 us; speedup vs baseline: 3.8784x; 1.2264x over previous
//
#include <hip/hip_runtime.h>
#include <hip/hip_bf16.h>

typedef __hip_bfloat16 bf16;
typedef __attribute__((ext_vector_type(8))) short bf16x8;
typedef __attribute__((ext_vector_type(4))) float f32x4;

#define BDIM 4
#define CDIM 512
#define NHEADS 8
#define NGROUPS 4
#define GCH 128

__device__ __forceinline__ float bf2f(bf16 v) { return __bfloat162float(v); }
__device__ __forceinline__ float bfu2f(unsigned short u) {
  return __uint_as_float(((unsigned)u) << 16);
}

__device__ __forceinline__ float4 load4(const float* p) { return *reinterpret_cast<const float4*>(p); }
__device__ __forceinline__ float4 load4(const bf16* p) {
  ushort4 u = *reinterpret_cast<const ushort4*>(p);
  float4 r;
  r.x = __uint_as_float(((unsigned)u.x) << 16);
  r.y = __uint_as_float(((unsigned)u.y) << 16);
  r.z = __uint_as_float(((unsigned)u.z) << 16);
  r.w = __uint_as_float(((unsigned)u.w) << 16);
  return r;
}

__device__ __forceinline__ void stv(float* p, float v) { *p = v; }
__device__ __forceinline__ void stv(bf16* p, float v) { *p = __float2bfloat16(v); }

// out[b][o][n] = sum_c W[o][c] * in[b][c][n] + bias[o];  O=C=512, N=1024, B=4
template <typename InT, typename OutT>
__global__ __launch_bounds__(256) void conv1x1_kernel(
    const float* __restrict__ Wm, const float* __restrict__ bias,
    const InT* __restrict__ in, OutT* __restrict__ out) {
  __shared__ float Wt[16][64];  // [k][o]
  __shared__ float Xt[16][64];  // [k][n]
  const int b = blockIdx.z;
  const int o0 = blockIdx.y * 64;
  const int n0 = blockIdx.x * 64;
  const int t = threadIdx.x;
  const int tx = t & 15, ty = t >> 4;
  const int lw_o = t >> 2, lw_k = (t & 3) * 4;
  const int lx_k = t >> 4, lx_n = (t & 15) * 4;
  float acc[4][4] = {};
  for (int k0 = 0; k0 < CDIM; k0 += 16) {
    float4 wv = load4(Wm + (size_t)(o0 + lw_o) * CDIM + k0 + lw_k);
    Wt[lw_k + 0][lw_o] = wv.x;
    Wt[lw_k + 1][lw_o] = wv.y;
    Wt[lw_k + 2][lw_o] = wv.z;
    Wt[lw_k + 3][lw_o] = wv.w;
    float4 xv = load4(in + ((size_t)b * CDIM + k0 + lx_k) * 1024 + n0 + lx_n);
    *reinterpret_cast<float4*>(&Xt[lx_k][lx_n]) = xv;
    __syncthreads();
#pragma unroll
    for (int k = 0; k < 16; k++) {
      const float4 a = *reinterpret_cast<const float4*>(&Wt[k][ty * 4]);
      const float4 x = *reinterpret_cast<const float4*>(&Xt[k][tx * 4]);
      const float av[4] = {a.x, a.y, a.z, a.w};
      const float xv2[4] = {x.x, x.y, x.z, x.w};
#pragma unroll
      for (int j = 0; j < 4; j++)
#pragma unroll
        for (int i = 0; i < 4; i++) acc[j][i] += av[j] * xv2[i];
    }
    __syncthreads();
  }
#pragma unroll
  for (int j = 0; j < 4; j++) {
    const int o = o0 + ty * 4 + j;
    const float bv = bias[o];
#pragma unroll
    for (int i = 0; i < 4; i++)
      stv(out + ((size_t)b * CDIM + o) * 1024 + n0 + tx * 4 + i, acc[j][i] + bv);
  }
}

// depthwise 5x5 conv + LayerNorm(128) + exact GELU + 1x1(128->2) + tanh -> pos
__global__ __launch_bounds__(128) void offset_kernel(
    const bf16* __restrict__ q, const float* __restrict__ dw_w,
    const float* __restrict__ dw_b, const float* __restrict__ ln_g,
    const float* __restrict__ ln_b, const float* __restrict__ off_w,
    float* __restrict__ pos, float* __restrict__ out_pos, float* __restrict__ out_ref) {
  const int bg = blockIdx.x;  // 0..15
  const int h = blockIdx.y;   // 0..31
  const int c = threadIdx.x;  // 0..127 (channel)
  const int b = bg >> 2, g = bg & 3;
  const bf16* qp = q + ((size_t)b * CDIM + g * GCH + c) * 1024;
  float wgt[25];
#pragma unroll
  for (int i = 0; i < 25; i++) wgt[i] = dw_w[c * 25 + i];
  const float cbias = dw_b[c];
  const float gam = ln_g[c], bet = ln_b[c];
  const float ow0 = off_w[c], ow1 = off_w[GCH + c];
  __shared__ float red[8];
  for (int w = 0; w < 32; w++) {
    float s = cbias;
#pragma unroll
    for (int ky = 0; ky < 5; ky++) {
      const int y = h + ky - 2;
      if (y < 0 || y >= 32) continue;
#pragma unroll
      for (int kx = 0; kx < 5; kx++) {
        const int x = w + kx - 2;
        if (x < 0 || x >= 32) continue;
        s += wgt[ky * 5 + kx] * bf2f(qp[y * 32 + x]);
      }
    }
    float ssum = s, ssq = s * s;
#pragma unroll
    for (int o = 1; o < 64; o <<= 1) {
      ssum += __shfl_xor(ssum, o);
      ssq += __shfl_xor(ssq, o);
    }
    if ((c & 63) == 0) { red[c >> 6] = ssum; red[2 + (c >> 6)] = ssq; }
    __syncthreads();
    const float mu = (red[0] + red[1]) * (1.0f / 128.0f);
    const float var = (red[2] + red[3]) * (1.0f / 128.0f) - mu * mu;
    const float xn = (s - mu) * rsqrtf(var + 1e-5f) * gam + bet;
    const float ge = 0.5f * xn * (1.0f + erff(xn * 0.70710678118654752f));
    float p0 = ow0 * ge, p1 = ow1 * ge;
#pragma unroll
    for (int o = 1; o < 64; o <<= 1) {
      p0 += __shfl_xor(p0, o);
      p1 += __shfl_xor(p1, o);
    }
    if ((c & 63) == 0) { red[4 + (c >> 6)] = p0; red[6 + (c >> 6)] = p1; }
    __syncthreads();
    if (c == 0) {
      const float oy = tanhf(red[4] + red[5]) * 0.0625f;  // (1/32)*2
      const float ox = tanhf(red[6] + red[7]) * 0.0625f;
      const float ry = ((float)h + 0.5f) * (2.0f / 32.0f) - 1.0f;
      const float rx = ((float)w + 0.5f) * (2.0f / 32.0f) - 1.0f;
      const float py = oy + ry, px = ox + rx;
      const size_t idx = (size_t)bg * 1024 + h * 32 + w;
      pos[idx * 2] = py;
      pos[idx * 2 + 1] = px;
      out_pos[idx * 2] = py;
      out_pos[idx * 2 + 1] = px;
      out_ref[idx * 2] = ry;
      out_ref[idx * 2 + 1] = rx;
    }
    __syncthreads();
  }
}

// bilinear grid-sample of x at pos -> xs [16][128][1024]
__global__ __launch_bounds__(256) void sample_kernel(
    const float* __restrict__ x, const float* __restrict__ pos, bf16* __restrict__ xs) {
  const int bg = blockIdx.x, c = blockIdx.y;
  const int b = bg >> 2, g = bg & 3;
  __shared__ float plane[1024];
  const float* xp = x + ((size_t)b * CDIM + g * GCH + c) * 1024;
  for (int i = threadIdx.x; i < 1024; i += 256) plane[i] = xp[i];
  __syncthreads();
  for (int s = threadIdx.x; s < 1024; s += 256) {
    const float py = pos[((size_t)bg * 1024 + s) * 2];
    const float px = pos[((size_t)bg * 1024 + s) * 2 + 1];
    const float gx = (px + 1.0f) * 15.5f;  // align_corners=True, W=32
    const float gy = (py + 1.0f) * 15.5f;
    const float x0f = floorf(gx), y0f = floorf(gy);
    const float wx = gx - x0f, wy = gy - y0f;
    const int ix = (int)x0f, iy = (int)y0f;
    float r = 0.0f;
    const bool vx0 = (ix >= 0) & (ix <= 31), vx1 = (ix + 1 >= 0) & (ix + 1 <= 31);
    const bool vy0 = (iy >= 0) & (iy <= 31), vy1 = (iy + 1 >= 0) & (iy + 1 <= 31);
    if (vy0 && vx0) r += plane[iy * 32 + ix] * (1.0f - wx) * (1.0f - wy);
    if (vy0 && vx1) r += plane[iy * 32 + ix + 1] * wx * (1.0f - wy);
    if (vy1 && vx0) r += plane[(iy + 1) * 32 + ix] * (1.0f - wx) * wy;
    if (vy1 && vx1) r += plane[(iy + 1) * 32 + ix + 1] * wx * wy;
    xs[((size_t)bg * GCH + c) * 1024 + s] = __float2bfloat16(r);
  }
}

// MFMA fused attention. 4 waves/block; wave w owns cols [16w,16w+16) of S (QK)
// and of O (PV). Frag layouts (mfma_f32_16x16x32_bf16, m97-lineage verified):
//   A: row=l&15, k=8*(l>>4)+j (16B contig)   B: col=l&15, k=8*(l>>4)+j
//   D: col=l&15, row=4*(l>>4)+reg
// LDS tiles XOR-swizzled byte^=((row&7)<<4) to kill 16-way frag-read conflicts.
__global__ __launch_bounds__(256) void attn_kernel(
    const bf16* __restrict__ q, const bf16* __restrict__ kk,
    const bf16* __restrict__ vv, const float* __restrict__ pos,
    const float* __restrict__ rpe, bf16* __restrict__ ao) {
  __shared__ __align__(16) unsigned char k_lds[64 * 128];  // K^T tile [n][c] bf16 swz
  __shared__ __align__(16) unsigned char v_lds[64 * 128];  // V tile  [c][n] bf16 swz
  __shared__ __align__(16) unsigned char p_lds[32 * 128];  // P       [m][n] bf16 swz
  __shared__ unsigned short rpe_s[63 * 63];                // bf16 table
  __shared__ __align__(16) float red_max[32][4];
  __shared__ __align__(16) float red_sum[32][4];

  const int bh = blockIdx.y;       // 0..31
  const int m0 = blockIdx.x * 32;  // query tile base
  const int b = bh >> 3, h = bh & 7;
  const int g = h >> 1;
  const int bg = b * 4 + g;
  const int t = threadIdx.x, l = t & 63, w = t >> 6;
  const int rg = l >> 4, cl = l & 15;
  const size_t hbase = ((size_t)b * CDIM + h * 64) * 1024;
  const unsigned short* qu = (const unsigned short*)q;

  for (int i = t; i < 63 * 63; i += 256)
    rpe_s[i] = __hip_bfloat16_raw(__float2bfloat16(rpe[h * 3969 + i])).x;

  // Q A-frags (persistent): aq[mh][kc]: Q[m0+16mh+(l&15)][32kc+8rg+j]
  bf16x8 aq[2][2];
#pragma unroll
  for (int mh = 0; mh < 2; mh++)
#pragma unroll
    for (int kc = 0; kc < 2; kc++) {
      bf16x8 a;
#pragma unroll
      for (int j = 0; j < 8; j++)
        a[j] = (short)qu[hbase + (size_t)(32 * kc + 8 * rg + j) * 1024 + m0 + 16 * mh + cl];
      aq[mh][kc] = a;
    }

  const float qyc = ((float)(m0 >> 5) + 0.5f) * (2.0f / 32.0f) - 1.0f;  // const per block
  float rmax[8], rsum[8], corr[8];
#pragma unroll
  for (int i = 0; i < 8; i++) { rmax[i] = -1e30f; rsum[i] = 0.0f; }
  f32x4 oacc[2] = {{0.f, 0.f, 0.f, 0.f}, {0.f, 0.f, 0.f, 0.f}};

  const float* posb = pos + (size_t)bg * 2048;
  const int ntile = 16 * w + cl;  // this lane's col within tile (S-col n / O-col c)
  // staging maps
  const int kc2 = (t & 31) * 2;   // K-pack: channel pair
  const int kn8 = (t >> 5) * 8;   // K-pack: n block
  const int vc = t >> 2;          // V copy: row c
  const int vh = (t & 3) * 32;    // V copy: byte offset

  for (int n0 = 0; n0 < 1024; n0 += 64) {
    // ---- stage: K transpose-pack [c][n]->[n][c], V raw copy; both swizzled ----
    {
      union { uint4 v; unsigned short hw[8]; } r0, r1;
      r0.v = *(const uint4*)(kk + hbase + (size_t)kc2 * 1024 + n0 + kn8);
      r1.v = *(const uint4*)(kk + hbase + (size_t)(kc2 + 1) * 1024 + n0 + kn8);
#pragma unroll
      for (int i = 0; i < 8; i++) {
        const int n = kn8 + i;
        const unsigned v32 = (unsigned)r0.hw[i] | ((unsigned)r1.hw[i] << 16);
        *(unsigned*)(k_lds + n * 128 + ((kc2 * 2) ^ ((n & 7) << 4))) = v32;
      }
      const uint4 s0 = *(const uint4*)(vv + hbase + (size_t)vc * 1024 + n0 + vh / 2);
      const uint4 s1 = *(const uint4*)(vv + hbase + (size_t)vc * 1024 + n0 + vh / 2 + 8);
      *(uint4*)(v_lds + vc * 128 + (vh ^ ((vc & 7) << 4))) = s0;
      *(uint4*)(v_lds + vc * 128 + ((vh + 16) ^ ((vc & 7) << 4))) = s1;
    }
    __syncthreads();  // staging visible (also covers rpe/first iter)

    // ---- QK^T (4 MFMA) ----
    f32x4 sf[2] = {{0.f, 0.f, 0.f, 0.f}, {0.f, 0.f, 0.f, 0.f}};
    {
      const unsigned swn = (unsigned)((ntile & 7) << 4);
      const bf16x8 bk0 = *(const bf16x8*)(k_lds + ntile * 128 + ((16 * rg) ^ swn));
      const bf16x8 bk1 = *(const bf16x8*)(k_lds + ntile * 128 + ((64 + 16 * rg) ^ swn));
      sf[0] = __builtin_amdgcn_mfma_f32_16x16x32_bf16(aq[0][0], bk0, sf[0], 0, 0, 0);
      sf[0] = __builtin_amdgcn_mfma_f32_16x16x32_bf16(aq[0][1], bk1, sf[0], 0, 0, 0);
      sf[1] = __builtin_amdgcn_mfma_f32_16x16x32_bf16(aq[1][0], bk0, sf[1], 0, 0, 0);
      sf[1] = __builtin_amdgcn_mfma_f32_16x16x32_bf16(aq[1][1], bk1, sf[1], 0, 0, 0);
    }

    // ---- bias in-fragment: lane's n fixed -> iy,wy once; 8 row lookups ----
    {
      const int npos = n0 + ntile;
      const float py = posb[2 * npos], px = posb[2 * npos + 1];
      const float gyc = ((qyc - py) * 0.5f + 1.0f) * 31.0f;
      const float y0f = floorf(gyc);
      const float wy = gyc - y0f;
      const int iy = (int)y0f;
      const bool vy0 = (iy >= 0) & (iy <= 62), vy1 = (iy + 1 >= 0) & (iy + 1 <= 62);
      const int ry0 = iy * 63, ry1 = ry0 + 63;
#pragma unroll
      for (int mh = 0; mh < 2; mh++)
#pragma unroll
        for (int r = 0; r < 4; r++) {
          const int mloc = 16 * mh + 4 * rg + r;
          const float qx = ((float)mloc + 0.5f) * (2.0f / 32.0f) - 1.0f;
          const float gxc = ((qx - px) * 0.5f + 1.0f) * 31.0f;
          const float x0f = floorf(gxc);
          const float wx = gxc - x0f;
          const int ix = (int)x0f;
          const bool vx0 = (ix >= 0) & (ix <= 62), vx1 = (ix + 1 >= 0) & (ix + 1 <= 62);
          float bias = 0.0f;
          if (vy0 && vx0) bias += bfu2f(rpe_s[ry0 + ix]) * (1.0f - wx) * (1.0f - wy);
          if (vy0 && vx1) bias += bfu2f(rpe_s[ry0 + ix + 1]) * wx * (1.0f - wy);
          if (vy1 && vx0) bias += bfu2f(rpe_s[ry1 + ix]) * (1.0f - wx) * wy;
          if (vy1 && vx1) bias += bfu2f(rpe_s[ry1 + ix + 1]) * wx * wy;
          sf[mh][r] = sf[mh][r] * 0.125f + bias;
        }
    }

    // ---- tile row-max partials (16-col shfl reduce) -> red_max ----
#pragma unroll
    for (int mh = 0; mh < 2; mh++)
#pragma unroll
      for (int r = 0; r < 4; r++) {
        float v = sf[mh][r];
#pragma unroll
        for (int o = 1; o < 16; o <<= 1) v = fmaxf(v, __shfl_xor(v, o));
        if (cl == 0) red_max[16 * mh + 4 * rg + r][w] = v;
      }
    __syncthreads();  // red_max visible

    // ---- global tile max, exp, P write, sum partials, O rescale ----
#pragma unroll
    for (int mh = 0; mh < 2; mh++)
#pragma unroll
      for (int r = 0; r < 4; r++) {
        const int i = mh * 4 + r;
        const int mloc = 16 * mh + 4 * rg + r;
        const f32x4 rm = *(const f32x4*)&red_max[mloc][0];
        const float gmax = fmaxf(fmaxf(rm[0], rm[1]), fmaxf(rm[2], rm[3]));
        const float nmax = fmaxf(rmax[i], gmax);
        corr[i] = __expf(rmax[i] - nmax);
        rmax[i] = nmax;
        const float p = __expf(sf[mh][r] - nmax);
        float s = p;
#pragma unroll
        for (int o = 1; o < 16; o <<= 1) s += __shfl_xor(s, o);
        if (cl == 0) red_sum[mloc][w] = s;
        *(unsigned short*)(p_lds + mloc * 128 + ((ntile * 2) ^ ((mloc & 7) << 4))) =
            __hip_bfloat16_raw(__float2bfloat16(p)).x;
        oacc[mh][r] *= corr[i];
      }
    __syncthreads();  // p_lds + red_sum visible

#pragma unroll
    for (int mh = 0; mh < 2; mh++)
#pragma unroll
      for (int r = 0; r < 4; r++) {
        const int i = mh * 4 + r;
        const f32x4 rs = *(const f32x4*)&red_sum[16 * mh + 4 * rg + r][0];
        rsum[i] = rsum[i] * corr[i] + (rs[0] + rs[1] + rs[2] + rs[3]);
      }

    // ---- PV (4 MFMA) ----
    {
      const unsigned swc = (unsigned)((ntile & 7) << 4);
      const bf16x8 bv0 = *(const bf16x8*)(v_lds + ntile * 128 + ((16 * rg) ^ swc));
      const bf16x8 bv1 = *(const bf16x8*)(v_lds + ntile * 128 + ((64 + 16 * rg) ^ swc));
#pragma unroll
      for (int mh = 0; mh < 2; mh++) {
        const int mrow = 16 * mh + cl;
        const unsigned swm = (unsigned)((mrow & 7) << 4);
        const bf16x8 pa0 = *(const bf16x8*)(p_lds + mrow * 128 + ((16 * rg) ^ swm));
        const bf16x8 pa1 = *(const bf16x8*)(p_lds + mrow * 128 + ((64 + 16 * rg) ^ swm));
        oacc[mh] = __builtin_amdgcn_mfma_f32_16x16x32_bf16(pa0, bv0, oacc[mh], 0, 0, 0);
        oacc[mh] = __builtin_amdgcn_mfma_f32_16x16x32_bf16(pa1, bv1, oacc[mh], 0, 0, 0);
      }
    }
    __syncthreads();  // PV reads done; next stage may overwrite
  }

  // ---- epilogue: normalize, stage f32 O[m][c] in (reused) k_lds, store bf16 ----
  float* o_st = (float*)k_lds;
#pragma unroll
  for (int mh = 0; mh < 2; mh++)
#pragma unroll
    for (int r = 0; r < 4; r++)
      o_st[(16 * mh + 4 * rg + r) * 64 + ntile] = oacc[mh][r] / rsum[mh * 4 + r];
  __syncthreads();
  {
    const int c = t >> 2, mb = (t & 3) * 8;
    unsigned u[4];
#pragma unroll
    for (int i = 0; i < 4; i++) {
      const unsigned short lo =
          __hip_bfloat16_raw(__float2bfloat16(o_st[(mb + 2 * i) * 64 + c])).x;
      const unsigned short hi =
          __hip_bfloat16_raw(__float2bfloat16(o_st[(mb + 2 * i + 1) * 64 + c])).x;
      u[i] = (unsigned)lo | ((unsigned)hi << 16);
    }
    uint4 outv = {u[0], u[1], u[2], u[3]};
    *(uint4*)(ao + hbase + (size_t)c * 1024 + m0 + mb) = outv;
  }
}

extern "C" void kernel_launch(void* const* d_in, const int* in_sizes, int n_in,
                              void* d_out, int out_size, void* d_ws, size_t ws_size,
                              hipStream_t stream) {
  const float* x    = (const float*)d_in[0];
  const float* w_q  = (const float*)d_in[1];
  const float* b_q  = (const float*)d_in[2];
  const float* w_k  = (const float*)d_in[3];
  const float* b_k  = (const float*)d_in[4];
  const float* w_v  = (const float*)d_in[5];
  const float* b_v  = (const float*)d_in[6];
  const float* w_o  = (const float*)d_in[7];
  const float* b_o  = (const float*)d_in[8];
  const float* dw_w = (const float*)d_in[9];
  const float* dw_b = (const float*)d_in[10];
  const float* ln_g = (const float*)d_in[11];
  const float* ln_b = (const float*)d_in[12];
  const float* off_w= (const float*)d_in[13];
  const float* rpe  = (const float*)d_in[14];

  // Outputs are FLOAT32 (reference returns f32 arrays).
  float* out_y   = (float*)d_out;            // [4,512,32,32]   (2097152 f32)
  float* out_pos = out_y + 2097152;          // [4,4,32,32,2]   (32768 f32)
  float* out_ref = out_pos + 32768;          // [4,4,32,32,2]   (32768 f32)

  // workspace: pos (f32, 128KB) first, then bf16 intermediates (4MB each).
  float* pos_ws = (float*)d_ws;              // 32768 floats
  bf16*  q_ws   = (bf16*)(pos_ws + 32768);   // 2097152 bf16
  bf16*  xs_ws  = q_ws + 2097152;            // 2097152 bf16 (reused as ao)
  bf16*  k_ws   = xs_ws + 2097152;
  bf16*  v_ws   = k_ws + 2097152;
  bf16*  ao_ws  = xs_ws;                     // xs dead after k/v convs

  conv1x1_kernel<float, bf16><<<dim3(16, 8, 4), 256, 0, stream>>>(w_q, b_q, x, q_ws);
  offset_kernel<<<dim3(16, 32), 128, 0, stream>>>(q_ws, dw_w, dw_b, ln_g, ln_b, off_w,
                                                  pos_ws, out_pos, out_ref);
  sample_kernel<<<dim3(16, 128), 256, 0, stream>>>(x, pos_ws, xs_ws);
  conv1x1_kernel<bf16, bf16><<<dim3(16, 8, 4), 256, 0, stream>>>(w_k, b_k, xs_ws, k_ws);
  conv1x1_kernel<bf16, bf16><<<dim3(16, 8, 4), 256, 0, stream>>>(w_v, b_v, xs_ws, v_ws);
  attn_kernel<<<dim3(32, 32), 256, 0, stream>>>(q_ws, k_ws, v_ws, pos_ws, rpe, ao_ws);
  conv1x1_kernel<bf16, float><<<dim3(16, 8, 4), 256, 0, stream>>>(w_o, b_o, ao_ws, out_y);
}

// Round 7
// 344.590 us; speedup vs baseline: 4.8891x; 1.2606x over previous
//
#include <hip/hip_runtime.h>
#include <hip/hip_bf16.h>

typedef __hip_bfloat16 bf16;
typedef __attribute__((ext_vector_type(8))) short bf16x8;
typedef __attribute__((ext_vector_type(4))) float f32x4;

#define BDIM 4
#define CDIM 512
#define NHEADS 8
#define NGROUPS 4
#define GCH 128

__device__ __forceinline__ float bf2f(bf16 v) { return __bfloat162float(v); }
__device__ __forceinline__ float bfu2f(unsigned short u) {
  return __uint_as_float(((unsigned)u) << 16);
}
__device__ __forceinline__ unsigned short f2bu(float v) {
  return __hip_bfloat16_raw(__float2bfloat16(v)).x;
}
__device__ __forceinline__ unsigned pack2(float lo, float hi) {
  return (unsigned)f2bu(lo) | ((unsigned)f2bu(hi) << 16);
}

__device__ __forceinline__ float4 load4(const bf16* p) {
  ushort4 u = *reinterpret_cast<const ushort4*>(p);
  float4 r;
  r.x = __uint_as_float(((unsigned)u.x) << 16);
  r.y = __uint_as_float(((unsigned)u.y) << 16);
  r.z = __uint_as_float(((unsigned)u.z) << 16);
  r.w = __uint_as_float(((unsigned)u.w) << 16);
  return r;
}

// ---- f32 -> bf16 conversion: x (2M) + 4 weight matrices (256K each) ----
__global__ __launch_bounds__(256) void cvt_kernel(
    const float* __restrict__ x, const float* __restrict__ wq,
    const float* __restrict__ wk, const float* __restrict__ wv,
    const float* __restrict__ wo, unsigned short* __restrict__ x_bf,
    unsigned short* __restrict__ w_bf) {
  const int seg = blockIdx.y;
  const float* src;
  unsigned short* dst;
  int count;
  if (seg == 0) { src = x; dst = x_bf; count = 2097152; }
  else {
    src = (seg == 1 ? wq : seg == 2 ? wk : seg == 3 ? wv : wo);
    dst = w_bf + (seg - 1) * 262144;
    count = 262144;
  }
  const int i = (blockIdx.x * 256 + threadIdx.x) * 8;
  if (i >= count) return;
  const float4 a = *(const float4*)(src + i);
  const float4 b = *(const float4*)(src + i + 4);
  uint4 u;
  u.x = pack2(a.x, a.y);
  u.y = pack2(a.z, a.w);
  u.z = pack2(b.x, b.y);
  u.w = pack2(b.z, b.w);
  *(uint4*)(dst + i) = u;
}

// ---- MFMA GEMM: out[b][o][n] = sum_c W[o][c]*in[b][c][n] + bias[o] ----
// 64x64 tile, BK=64, 4 waves each own a 32x32 quadrant (wr=w>>1, wc=w&1).
// Frag mapping (HW-verified in attn): A row=cl,k=8rg+j; B col=cl,k=8rg+j;
// D col=cl,row=4rg+r. LDS swizzle byte^=((row&7)<<4) on both tiles.
template <typename OutT>
__global__ __launch_bounds__(256) void gemm_kernel(
    const unsigned short* __restrict__ Wb,  // [512][512] bf16
    const float* __restrict__ bias,
    const unsigned short* __restrict__ in,  // [4][512][1024] bf16
    OutT* __restrict__ out) {
  __shared__ __align__(16) unsigned char smem[16384];
  unsigned char* a_lds = smem;         // [64 o][64 c] bf16 swz
  unsigned char* b_lds = smem + 8192;  // [64 n][64 c] bf16 swz
  const int b = blockIdx.z;
  const int o0 = blockIdx.y * 64;
  const int n0 = blockIdx.x * 64;
  const int t = threadIdx.x, l = t & 63, w = t >> 6;
  const int rg = l >> 4, cl = l & 15;
  const int o_base = (w >> 1) * 32, n_base = (w & 1) * 32;
  const unsigned short* inb = in + (size_t)b * 524288;
  // staging maps
  const int ao = t >> 2;          // A: o row 0..63
  const int ac8 = (t & 3) * 8;    // A: c chunk (and +32)
  const int kc2 = (t & 31) * 2;   // B: channel pair
  const int kn8 = (t >> 5) * 8;   // B: n block

  f32x4 acc[2][2] = {{{0.f,0.f,0.f,0.f},{0.f,0.f,0.f,0.f}},
                     {{0.f,0.f,0.f,0.f},{0.f,0.f,0.f,0.f}}};

  for (int k0 = 0; k0 < 512; k0 += 64) {
    // stage A (row-major copy, swizzled)
    {
      const uint4 wa = *(const uint4*)(Wb + (size_t)(o0 + ao) * 512 + k0 + ac8);
      const uint4 wb2 = *(const uint4*)(Wb + (size_t)(o0 + ao) * 512 + k0 + ac8 + 32);
      const unsigned swo = (unsigned)((ao & 7) << 4);
      *(uint4*)(a_lds + ao * 128 + ((2 * ac8) ^ swo)) = wa;
      *(uint4*)(a_lds + ao * 128 + ((2 * ac8 + 64) ^ swo)) = wb2;
    }
    // stage B (transpose-pack [c][n] -> [n][c], swizzled)
    {
      union { uint4 v; unsigned short hw[8]; } r0, r1;
      r0.v = *(const uint4*)(inb + (size_t)(k0 + kc2) * 1024 + n0 + kn8);
      r1.v = *(const uint4*)(inb + (size_t)(k0 + kc2 + 1) * 1024 + n0 + kn8);
#pragma unroll
      for (int i = 0; i < 8; i++) {
        const int n = kn8 + i;
        const unsigned v32 = (unsigned)r0.hw[i] | ((unsigned)r1.hw[i] << 16);
        *(unsigned*)(b_lds + n * 128 + ((2 * kc2) ^ ((n & 7) << 4))) = v32;
      }
    }
    __syncthreads();
#pragma unroll
    for (int kk = 0; kk < 2; kk++) {
      bf16x8 af[2], bfr[2];
#pragma unroll
      for (int m = 0; m < 2; m++) {
        const int o_loc = o_base + 16 * m + cl;
        af[m] = *(const bf16x8*)(a_lds + o_loc * 128 +
                                 ((64 * kk + 16 * rg) ^ ((o_loc & 7) << 4)));
      }
#pragma unroll
      for (int nn = 0; nn < 2; nn++) {
        const int n_loc = n_base + 16 * nn + cl;
        bfr[nn] = *(const bf16x8*)(b_lds + n_loc * 128 +
                                   ((64 * kk + 16 * rg) ^ ((n_loc & 7) << 4)));
      }
#pragma unroll
      for (int m = 0; m < 2; m++)
#pragma unroll
        for (int nn = 0; nn < 2; nn++)
          acc[m][nn] = __builtin_amdgcn_mfma_f32_16x16x32_bf16(af[m], bfr[nn],
                                                               acc[m][nn], 0, 0, 0);
    }
    __syncthreads();
  }

  // epilogue: stage f32 C tile in smem, then coalesced store + bias
  float* o_st = (float*)smem;  // [64][64]
#pragma unroll
  for (int m = 0; m < 2; m++)
#pragma unroll
    for (int nn = 0; nn < 2; nn++)
#pragma unroll
      for (int r = 0; r < 4; r++)
        o_st[(o_base + 16 * m + 4 * rg + r) * 64 + n_base + 16 * nn + cl] =
            acc[m][nn][r];
  __syncthreads();
  const int eo = t >> 4;
  const int en = (t & 15) * 4;
#pragma unroll
  for (int pass = 0; pass < 4; pass++) {
    const int o_loc = eo + pass * 16;
    const f32x4 v = *(const f32x4*)(o_st + o_loc * 64 + en);
    const float bv = bias[o0 + o_loc];
    if constexpr (sizeof(OutT) == 2) {
      ushort4 u;
      u.x = f2bu(v[0] + bv);
      u.y = f2bu(v[1] + bv);
      u.z = f2bu(v[2] + bv);
      u.w = f2bu(v[3] + bv);
      *(ushort4*)((bf16*)out + ((size_t)b * 512 + o0 + o_loc) * 1024 + n0 + en) = u;
    } else {
      float4 r = {v[0] + bv, v[1] + bv, v[2] + bv, v[3] + bv};
      *(float4*)((float*)out + ((size_t)b * 512 + o0 + o_loc) * 1024 + n0 + en) = r;
    }
  }
}

// depthwise 5x5 conv + LayerNorm(128) + exact GELU + 1x1(128->2) + tanh -> pos
__global__ __launch_bounds__(128) void offset_kernel(
    const bf16* __restrict__ q, const float* __restrict__ dw_w,
    const float* __restrict__ dw_b, const float* __restrict__ ln_g,
    const float* __restrict__ ln_b, const float* __restrict__ off_w,
    float* __restrict__ pos, float* __restrict__ out_pos, float* __restrict__ out_ref) {
  const int bg = blockIdx.x;  // 0..15
  const int h = blockIdx.y;   // 0..31
  const int c = threadIdx.x;  // 0..127 (channel)
  const int b = bg >> 2, g = bg & 3;
  const bf16* qp = q + ((size_t)b * CDIM + g * GCH + c) * 1024;
  float wgt[25];
#pragma unroll
  for (int i = 0; i < 25; i++) wgt[i] = dw_w[c * 25 + i];
  const float cbias = dw_b[c];
  const float gam = ln_g[c], bet = ln_b[c];
  const float ow0 = off_w[c], ow1 = off_w[GCH + c];
  __shared__ float red[8];
  for (int w = 0; w < 32; w++) {
    float s = cbias;
#pragma unroll
    for (int ky = 0; ky < 5; ky++) {
      const int y = h + ky - 2;
      if (y < 0 || y >= 32) continue;
#pragma unroll
      for (int kx = 0; kx < 5; kx++) {
        const int x = w + kx - 2;
        if (x < 0 || x >= 32) continue;
        s += wgt[ky * 5 + kx] * bf2f(qp[y * 32 + x]);
      }
    }
    float ssum = s, ssq = s * s;
#pragma unroll
    for (int o = 1; o < 64; o <<= 1) {
      ssum += __shfl_xor(ssum, o);
      ssq += __shfl_xor(ssq, o);
    }
    if ((c & 63) == 0) { red[c >> 6] = ssum; red[2 + (c >> 6)] = ssq; }
    __syncthreads();
    const float mu = (red[0] + red[1]) * (1.0f / 128.0f);
    const float var = (red[2] + red[3]) * (1.0f / 128.0f) - mu * mu;
    const float xn = (s - mu) * rsqrtf(var + 1e-5f) * gam + bet;
    const float ge = 0.5f * xn * (1.0f + erff(xn * 0.70710678118654752f));
    float p0 = ow0 * ge, p1 = ow1 * ge;
#pragma unroll
    for (int o = 1; o < 64; o <<= 1) {
      p0 += __shfl_xor(p0, o);
      p1 += __shfl_xor(p1, o);
    }
    if ((c & 63) == 0) { red[4 + (c >> 6)] = p0; red[6 + (c >> 6)] = p1; }
    __syncthreads();
    if (c == 0) {
      const float oy = tanhf(red[4] + red[5]) * 0.0625f;  // (1/32)*2
      const float ox = tanhf(red[6] + red[7]) * 0.0625f;
      const float ry = ((float)h + 0.5f) * (2.0f / 32.0f) - 1.0f;
      const float rx = ((float)w + 0.5f) * (2.0f / 32.0f) - 1.0f;
      const float py = oy + ry, px = ox + rx;
      const size_t idx = (size_t)bg * 1024 + h * 32 + w;
      pos[idx * 2] = py;
      pos[idx * 2 + 1] = px;
      out_pos[idx * 2] = py;
      out_pos[idx * 2 + 1] = px;
      out_ref[idx * 2] = ry;
      out_ref[idx * 2 + 1] = rx;
    }
    __syncthreads();
  }
}

// bilinear grid-sample of x at pos -> xs [16][128][1024]
__global__ __launch_bounds__(256) void sample_kernel(
    const float* __restrict__ x, const float* __restrict__ pos, bf16* __restrict__ xs) {
  const int bg = blockIdx.x, c = blockIdx.y;
  const int b = bg >> 2, g = bg & 3;
  __shared__ float plane[1024];
  const float* xp = x + ((size_t)b * CDIM + g * GCH + c) * 1024;
  for (int i = threadIdx.x; i < 1024; i += 256) plane[i] = xp[i];
  __syncthreads();
  for (int s = threadIdx.x; s < 1024; s += 256) {
    const float py = pos[((size_t)bg * 1024 + s) * 2];
    const float px = pos[((size_t)bg * 1024 + s) * 2 + 1];
    const float gx = (px + 1.0f) * 15.5f;  // align_corners=True, W=32
    const float gy = (py + 1.0f) * 15.5f;
    const float x0f = floorf(gx), y0f = floorf(gy);
    const float wx = gx - x0f, wy = gy - y0f;
    const int ix = (int)x0f, iy = (int)y0f;
    float r = 0.0f;
    const bool vx0 = (ix >= 0) & (ix <= 31), vx1 = (ix + 1 >= 0) & (ix + 1 <= 31);
    const bool vy0 = (iy >= 0) & (iy <= 31), vy1 = (iy + 1 >= 0) & (iy + 1 <= 31);
    if (vy0 && vx0) r += plane[iy * 32 + ix] * (1.0f - wx) * (1.0f - wy);
    if (vy0 && vx1) r += plane[iy * 32 + ix + 1] * wx * (1.0f - wy);
    if (vy1 && vx0) r += plane[(iy + 1) * 32 + ix] * (1.0f - wx) * wy;
    if (vy1 && vx1) r += plane[(iy + 1) * 32 + ix + 1] * wx * wy;
    xs[((size_t)bg * GCH + c) * 1024 + s] = __float2bfloat16(r);
  }
}

// MFMA fused attention (unchanged from round 6; HW-verified).
__global__ __launch_bounds__(256) void attn_kernel(
    const bf16* __restrict__ q, const bf16* __restrict__ kk,
    const bf16* __restrict__ vv, const float* __restrict__ pos,
    const float* __restrict__ rpe, bf16* __restrict__ ao) {
  __shared__ __align__(16) unsigned char k_lds[64 * 128];  // K^T tile [n][c] bf16 swz
  __shared__ __align__(16) unsigned char v_lds[64 * 128];  // V tile  [c][n] bf16 swz
  __shared__ __align__(16) unsigned char p_lds[32 * 128];  // P       [m][n] bf16 swz
  __shared__ unsigned short rpe_s[63 * 63];                // bf16 table
  __shared__ __align__(16) float red_max[32][4];
  __shared__ __align__(16) float red_sum[32][4];

  const int bh = blockIdx.y;       // 0..31
  const int m0 = blockIdx.x * 32;  // query tile base
  const int b = bh >> 3, h = bh & 7;
  const int g = h >> 1;
  const int bg = b * 4 + g;
  const int t = threadIdx.x, l = t & 63, w = t >> 6;
  const int rg = l >> 4, cl = l & 15;
  const size_t hbase = ((size_t)b * CDIM + h * 64) * 1024;
  const unsigned short* qu = (const unsigned short*)q;

  for (int i = t; i < 63 * 63; i += 256)
    rpe_s[i] = f2bu(rpe[h * 3969 + i]);

  // Q A-frags (persistent): aq[mh][kc]: Q[m0+16mh+(l&15)][32kc+8rg+j]
  bf16x8 aq[2][2];
#pragma unroll
  for (int mh = 0; mh < 2; mh++)
#pragma unroll
    for (int kc = 0; kc < 2; kc++) {
      bf16x8 a;
#pragma unroll
      for (int j = 0; j < 8; j++)
        a[j] = (short)qu[hbase + (size_t)(32 * kc + 8 * rg + j) * 1024 + m0 + 16 * mh + cl];
      aq[mh][kc] = a;
    }

  const float qyc = ((float)(m0 >> 5) + 0.5f) * (2.0f / 32.0f) - 1.0f;  // const per block
  float rmax[8], rsum[8], corr[8];
#pragma unroll
  for (int i = 0; i < 8; i++) { rmax[i] = -1e30f; rsum[i] = 0.0f; }
  f32x4 oacc[2] = {{0.f, 0.f, 0.f, 0.f}, {0.f, 0.f, 0.f, 0.f}};

  const float* posb = pos + (size_t)bg * 2048;
  const int ntile = 16 * w + cl;  // this lane's col within tile (S-col n / O-col c)
  // staging maps
  const int kc2 = (t & 31) * 2;   // K-pack: channel pair
  const int kn8 = (t >> 5) * 8;   // K-pack: n block
  const int vc = t >> 2;          // V copy: row c
  const int vh = (t & 3) * 32;    // V copy: byte offset

  for (int n0 = 0; n0 < 1024; n0 += 64) {
    // ---- stage: K transpose-pack [c][n]->[n][c], V raw copy; both swizzled ----
    {
      union { uint4 v; unsigned short hw[8]; } r0, r1;
      r0.v = *(const uint4*)(kk + hbase + (size_t)kc2 * 1024 + n0 + kn8);
      r1.v = *(const uint4*)(kk + hbase + (size_t)(kc2 + 1) * 1024 + n0 + kn8);
#pragma unroll
      for (int i = 0; i < 8; i++) {
        const int n = kn8 + i;
        const unsigned v32 = (unsigned)r0.hw[i] | ((unsigned)r1.hw[i] << 16);
        *(unsigned*)(k_lds + n * 128 + ((kc2 * 2) ^ ((n & 7) << 4))) = v32;
      }
      const uint4 s0 = *(const uint4*)(vv + hbase + (size_t)vc * 1024 + n0 + vh / 2);
      const uint4 s1 = *(const uint4*)(vv + hbase + (size_t)vc * 1024 + n0 + vh / 2 + 8);
      *(uint4*)(v_lds + vc * 128 + (vh ^ ((vc & 7) << 4))) = s0;
      *(uint4*)(v_lds + vc * 128 + ((vh + 16) ^ ((vc & 7) << 4))) = s1;
    }
    __syncthreads();  // staging visible (also covers rpe/first iter)

    // ---- QK^T (4 MFMA) ----
    f32x4 sf[2] = {{0.f, 0.f, 0.f, 0.f}, {0.f, 0.f, 0.f, 0.f}};
    {
      const unsigned swn = (unsigned)((ntile & 7) << 4);
      const bf16x8 bk0 = *(const bf16x8*)(k_lds + ntile * 128 + ((16 * rg) ^ swn));
      const bf16x8 bk1 = *(const bf16x8*)(k_lds + ntile * 128 + ((64 + 16 * rg) ^ swn));
      sf[0] = __builtin_amdgcn_mfma_f32_16x16x32_bf16(aq[0][0], bk0, sf[0], 0, 0, 0);
      sf[0] = __builtin_amdgcn_mfma_f32_16x16x32_bf16(aq[0][1], bk1, sf[0], 0, 0, 0);
      sf[1] = __builtin_amdgcn_mfma_f32_16x16x32_bf16(aq[1][0], bk0, sf[1], 0, 0, 0);
      sf[1] = __builtin_amdgcn_mfma_f32_16x16x32_bf16(aq[1][1], bk1, sf[1], 0, 0, 0);
    }

    // ---- bias in-fragment: lane's n fixed -> iy,wy once; 8 row lookups ----
    {
      const int npos = n0 + ntile;
      const float py = posb[2 * npos], px = posb[2 * npos + 1];
      const float gyc = ((qyc - py) * 0.5f + 1.0f) * 31.0f;
      const float y0f = floorf(gyc);
      const float wy = gyc - y0f;
      const int iy = (int)y0f;
      const bool vy0 = (iy >= 0) & (iy <= 62), vy1 = (iy + 1 >= 0) & (iy + 1 <= 62);
      const int ry0 = iy * 63, ry1 = ry0 + 63;
#pragma unroll
      for (int mh = 0; mh < 2; mh++)
#pragma unroll
        for (int r = 0; r < 4; r++) {
          const int mloc = 16 * mh + 4 * rg + r;
          const float qx = ((float)mloc + 0.5f) * (2.0f / 32.0f) - 1.0f;
          const float gxc = ((qx - px) * 0.5f + 1.0f) * 31.0f;
          const float x0f = floorf(gxc);
          const float wx = gxc - x0f;
          const int ix = (int)x0f;
          const bool vx0 = (ix >= 0) & (ix <= 62), vx1 = (ix + 1 >= 0) & (ix + 1 <= 62);
          float bias = 0.0f;
          if (vy0 && vx0) bias += bfu2f(rpe_s[ry0 + ix]) * (1.0f - wx) * (1.0f - wy);
          if (vy0 && vx1) bias += bfu2f(rpe_s[ry0 + ix + 1]) * wx * (1.0f - wy);
          if (vy1 && vx0) bias += bfu2f(rpe_s[ry1 + ix]) * (1.0f - wx) * wy;
          if (vy1 && vx1) bias += bfu2f(rpe_s[ry1 + ix + 1]) * wx * wy;
          sf[mh][r] = sf[mh][r] * 0.125f + bias;
        }
    }

    // ---- tile row-max partials (16-col shfl reduce) -> red_max ----
#pragma unroll
    for (int mh = 0; mh < 2; mh++)
#pragma unroll
      for (int r = 0; r < 4; r++) {
        float v = sf[mh][r];
#pragma unroll
        for (int o = 1; o < 16; o <<= 1) v = fmaxf(v, __shfl_xor(v, o));
        if (cl == 0) red_max[16 * mh + 4 * rg + r][w] = v;
      }
    __syncthreads();  // red_max visible

    // ---- global tile max, exp, P write, sum partials, O rescale ----
#pragma unroll
    for (int mh = 0; mh < 2; mh++)
#pragma unroll
      for (int r = 0; r < 4; r++) {
        const int i = mh * 4 + r;
        const int mloc = 16 * mh + 4 * rg + r;
        const f32x4 rm = *(const f32x4*)&red_max[mloc][0];
        const float gmax = fmaxf(fmaxf(rm[0], rm[1]), fmaxf(rm[2], rm[3]));
        const float nmax = fmaxf(rmax[i], gmax);
        corr[i] = __expf(rmax[i] - nmax);
        rmax[i] = nmax;
        const float p = __expf(sf[mh][r] - nmax);
        float s = p;
#pragma unroll
        for (int o = 1; o < 16; o <<= 1) s += __shfl_xor(s, o);
        if (cl == 0) red_sum[mloc][w] = s;
        *(unsigned short*)(p_lds + mloc * 128 + ((ntile * 2) ^ ((mloc & 7) << 4))) =
            f2bu(p);
        oacc[mh][r] *= corr[i];
      }
    __syncthreads();  // p_lds + red_sum visible

#pragma unroll
    for (int mh = 0; mh < 2; mh++)
#pragma unroll
      for (int r = 0; r < 4; r++) {
        const int i = mh * 4 + r;
        const f32x4 rs = *(const f32x4*)&red_sum[16 * mh + 4 * rg + r][0];
        rsum[i] = rsum[i] * corr[i] + (rs[0] + rs[1] + rs[2] + rs[3]);
      }

    // ---- PV (4 MFMA) ----
    {
      const unsigned swc = (unsigned)((ntile & 7) << 4);
      const bf16x8 bv0 = *(const bf16x8*)(v_lds + ntile * 128 + ((16 * rg) ^ swc));
      const bf16x8 bv1 = *(const bf16x8*)(v_lds + ntile * 128 + ((64 + 16 * rg) ^ swc));
#pragma unroll
      for (int mh = 0; mh < 2; mh++) {
        const int mrow = 16 * mh + cl;
        const unsigned swm = (unsigned)((mrow & 7) << 4);
        const bf16x8 pa0 = *(const bf16x8*)(p_lds + mrow * 128 + ((16 * rg) ^ swm));
        const bf16x8 pa1 = *(const bf16x8*)(p_lds + mrow * 128 + ((64 + 16 * rg) ^ swm));
        oacc[mh] = __builtin_amdgcn_mfma_f32_16x16x32_bf16(pa0, bv0, oacc[mh], 0, 0, 0);
        oacc[mh] = __builtin_amdgcn_mfma_f32_16x16x32_bf16(pa1, bv1, oacc[mh], 0, 0, 0);
      }
    }
    __syncthreads();  // PV reads done; next stage may overwrite
  }

  // ---- epilogue: normalize, stage f32 O[m][c] in (reused) k_lds, store bf16 ----
  float* o_st = (float*)k_lds;
#pragma unroll
  for (int mh = 0; mh < 2; mh++)
#pragma unroll
    for (int r = 0; r < 4; r++)
      o_st[(16 * mh + 4 * rg + r) * 64 + ntile] = oacc[mh][r] / rsum[mh * 4 + r];
  __syncthreads();
  {
    const int c = t >> 2, mb = (t & 3) * 8;
    unsigned u[4];
#pragma unroll
    for (int i = 0; i < 4; i++)
      u[i] = pack2(o_st[(mb + 2 * i) * 64 + c], o_st[(mb + 2 * i + 1) * 64 + c]);
    uint4 outv = {u[0], u[1], u[2], u[3]};
    *(uint4*)(ao + hbase + (size_t)c * 1024 + m0 + mb) = outv;
  }
}

extern "C" void kernel_launch(void* const* d_in, const int* in_sizes, int n_in,
                              void* d_out, int out_size, void* d_ws, size_t ws_size,
                              hipStream_t stream) {
  const float* x    = (const float*)d_in[0];
  const float* w_q  = (const float*)d_in[1];
  const float* b_q  = (const float*)d_in[2];
  const float* w_k  = (const float*)d_in[3];
  const float* b_k  = (const float*)d_in[4];
  const float* w_v  = (const float*)d_in[5];
  const float* b_v  = (const float*)d_in[6];
  const float* w_o  = (const float*)d_in[7];
  const float* b_o  = (const float*)d_in[8];
  const float* dw_w = (const float*)d_in[9];
  const float* dw_b = (const float*)d_in[10];
  const float* ln_g = (const float*)d_in[11];
  const float* ln_b = (const float*)d_in[12];
  const float* off_w= (const float*)d_in[13];
  const float* rpe  = (const float*)d_in[14];

  // Outputs are FLOAT32 (reference returns f32 arrays).
  float* out_y   = (float*)d_out;            // [4,512,32,32]   (2097152 f32)
  float* out_pos = out_y + 2097152;          // [4,4,32,32,2]   (32768 f32)
  float* out_ref = out_pos + 32768;          // [4,4,32,32,2]   (32768 f32)

  // workspace (~18.1 MB): pos f32, then bf16 buffers. x_bf aliases k_ws
  // (x_bf dead before conv_k writes k_ws).
  float* pos_ws = (float*)d_ws;              // 32768 f32
  bf16*  q_ws   = (bf16*)(pos_ws + 32768);   // 2097152 bf16
  bf16*  xs_ws  = q_ws + 2097152;            // 2097152 (reused as ao)
  bf16*  k_ws   = xs_ws + 2097152;           // 2097152 (first used as x_bf)
  bf16*  v_ws   = k_ws + 2097152;            // 2097152
  bf16*  w_bf   = v_ws + 2097152;            // 4*262144 bf16 weights
  bf16*  x_bf   = k_ws;
  bf16*  ao_ws  = xs_ws;

  unsigned short* w_bfu = (unsigned short*)w_bf;

  cvt_kernel<<<dim3(1024, 5), 256, 0, stream>>>(x, w_q, w_k, w_v, w_o,
                                                (unsigned short*)x_bf, w_bfu);
  gemm_kernel<bf16><<<dim3(16, 8, 4), 256, 0, stream>>>(
      w_bfu, b_q, (const unsigned short*)x_bf, q_ws);
  offset_kernel<<<dim3(16, 32), 128, 0, stream>>>(q_ws, dw_w, dw_b, ln_g, ln_b, off_w,
                                                  pos_ws, out_pos, out_ref);
  sample_kernel<<<dim3(16, 128), 256, 0, stream>>>(x, pos_ws, xs_ws);
  gemm_kernel<bf16><<<dim3(16, 8, 4), 256, 0, stream>>>(
      w_bfu + 262144, b_k, (const unsigned short*)xs_ws, k_ws);
  gemm_kernel<bf16><<<dim3(16, 8, 4), 256, 0, stream>>>(
      w_bfu + 2 * 262144, b_v, (const unsigned short*)xs_ws, v_ws);
  attn_kernel<<<dim3(32, 32), 256, 0, stream>>>(q_ws, k_ws, v_ws, pos_ws, rpe, ao_ws);
  gemm_kernel<float><<<dim3(16, 8, 4), 256, 0, stream>>>(
      w_bfu + 3 * 262144, b_o, (const unsigned short*)ao_ws, out_y);
}

// Round 8
// 247.939 us; speedup vs baseline: 6.7950x; 1.3898x over previous
//
#include <hip/hip_runtime.h>
#include <hip/hip_bf16.h>

typedef __hip_bfloat16 bf16;
typedef __attribute__((ext_vector_type(8))) short bf16x8;
typedef __attribute__((ext_vector_type(4))) float f32x4;

#define BDIM 4
#define CDIM 512
#define NHEADS 8
#define NGROUPS 4
#define GCH 128

__device__ __forceinline__ float bf2f(bf16 v) { return __bfloat162float(v); }
__device__ __forceinline__ float bfu2f(unsigned short u) {
  return __uint_as_float(((unsigned)u) << 16);
}
__device__ __forceinline__ unsigned short f2bu(float v) {
  return __hip_bfloat16_raw(__float2bfloat16(v)).x;
}
__device__ __forceinline__ unsigned pack2(float lo, float hi) {
  return (unsigned)f2bu(lo) | ((unsigned)f2bu(hi) << 16);
}

// ---- f32 -> bf16 conversion: x (2M) + 4 weight matrices (256K each) ----
__global__ __launch_bounds__(256) void cvt_kernel(
    const float* __restrict__ x, const float* __restrict__ wq,
    const float* __restrict__ wk, const float* __restrict__ wv,
    const float* __restrict__ wo, unsigned short* __restrict__ x_bf,
    unsigned short* __restrict__ w_bf) {
  const int seg = blockIdx.y;
  const float* src;
  unsigned short* dst;
  int count;
  if (seg == 0) { src = x; dst = x_bf; count = 2097152; }
  else {
    src = (seg == 1 ? wq : seg == 2 ? wk : seg == 3 ? wv : wo);
    dst = w_bf + (seg - 1) * 262144;
    count = 262144;
  }
  const int i = (blockIdx.x * 256 + threadIdx.x) * 8;
  if (i >= count) return;
  const float4 a = *(const float4*)(src + i);
  const float4 b = *(const float4*)(src + i + 4);
  uint4 u;
  u.x = pack2(a.x, a.y);
  u.y = pack2(a.z, a.w);
  u.z = pack2(b.x, b.y);
  u.w = pack2(b.z, b.w);
  *(uint4*)(dst + i) = u;
}

// ---- MFMA GEMM (unchanged from round 7; verified) ----
template <typename OutT>
__global__ __launch_bounds__(256) void gemm_kernel(
    const unsigned short* __restrict__ Wb,  // [512][512] bf16
    const float* __restrict__ bias,
    const unsigned short* __restrict__ in,  // [4][512][1024] bf16
    OutT* __restrict__ out) {
  __shared__ __align__(16) unsigned char smem[16384];
  unsigned char* a_lds = smem;         // [64 o][64 c] bf16 swz
  unsigned char* b_lds = smem + 8192;  // [64 n][64 c] bf16 swz
  const int b = blockIdx.z;
  const int o0 = blockIdx.y * 64;
  const int n0 = blockIdx.x * 64;
  const int t = threadIdx.x, l = t & 63, w = t >> 6;
  const int rg = l >> 4, cl = l & 15;
  const int o_base = (w >> 1) * 32, n_base = (w & 1) * 32;
  const unsigned short* inb = in + (size_t)b * 524288;
  const int ao = t >> 2;
  const int ac8 = (t & 3) * 8;
  const int kc2 = (t & 31) * 2;
  const int kn8 = (t >> 5) * 8;

  f32x4 acc[2][2] = {{{0.f,0.f,0.f,0.f},{0.f,0.f,0.f,0.f}},
                     {{0.f,0.f,0.f,0.f},{0.f,0.f,0.f,0.f}}};

  for (int k0 = 0; k0 < 512; k0 += 64) {
    {
      const uint4 wa = *(const uint4*)(Wb + (size_t)(o0 + ao) * 512 + k0 + ac8);
      const uint4 wb2 = *(const uint4*)(Wb + (size_t)(o0 + ao) * 512 + k0 + ac8 + 32);
      const unsigned swo = (unsigned)((ao & 7) << 4);
      *(uint4*)(a_lds + ao * 128 + ((2 * ac8) ^ swo)) = wa;
      *(uint4*)(a_lds + ao * 128 + ((2 * ac8 + 64) ^ swo)) = wb2;
    }
    {
      union { uint4 v; unsigned short hw[8]; } r0, r1;
      r0.v = *(const uint4*)(inb + (size_t)(k0 + kc2) * 1024 + n0 + kn8);
      r1.v = *(const uint4*)(inb + (size_t)(k0 + kc2 + 1) * 1024 + n0 + kn8);
#pragma unroll
      for (int i = 0; i < 8; i++) {
        const int n = kn8 + i;
        const unsigned v32 = (unsigned)r0.hw[i] | ((unsigned)r1.hw[i] << 16);
        *(unsigned*)(b_lds + n * 128 + ((2 * kc2) ^ ((n & 7) << 4))) = v32;
      }
    }
    __syncthreads();
#pragma unroll
    for (int kk = 0; kk < 2; kk++) {
      bf16x8 af[2], bfr[2];
#pragma unroll
      for (int m = 0; m < 2; m++) {
        const int o_loc = o_base + 16 * m + cl;
        af[m] = *(const bf16x8*)(a_lds + o_loc * 128 +
                                 ((64 * kk + 16 * rg) ^ ((o_loc & 7) << 4)));
      }
#pragma unroll
      for (int nn = 0; nn < 2; nn++) {
        const int n_loc = n_base + 16 * nn + cl;
        bfr[nn] = *(const bf16x8*)(b_lds + n_loc * 128 +
                                   ((64 * kk + 16 * rg) ^ ((n_loc & 7) << 4)));
      }
#pragma unroll
      for (int m = 0; m < 2; m++)
#pragma unroll
        for (int nn = 0; nn < 2; nn++)
          acc[m][nn] = __builtin_amdgcn_mfma_f32_16x16x32_bf16(af[m], bfr[nn],
                                                               acc[m][nn], 0, 0, 0);
    }
    __syncthreads();
  }

  float* o_st = (float*)smem;  // [64][64]
#pragma unroll
  for (int m = 0; m < 2; m++)
#pragma unroll
    for (int nn = 0; nn < 2; nn++)
#pragma unroll
      for (int r = 0; r < 4; r++)
        o_st[(o_base + 16 * m + 4 * rg + r) * 64 + n_base + 16 * nn + cl] =
            acc[m][nn][r];
  __syncthreads();
  const int eo = t >> 4;
  const int en = (t & 15) * 4;
#pragma unroll
  for (int pass = 0; pass < 4; pass++) {
    const int o_loc = eo + pass * 16;
    const f32x4 v = *(const f32x4*)(o_st + o_loc * 64 + en);
    const float bv = bias[o0 + o_loc];
    if constexpr (sizeof(OutT) == 2) {
      ushort4 u;
      u.x = f2bu(v[0] + bv);
      u.y = f2bu(v[1] + bv);
      u.z = f2bu(v[2] + bv);
      u.w = f2bu(v[3] + bv);
      *(ushort4*)((bf16*)out + ((size_t)b * 512 + o0 + o_loc) * 1024 + n0 + en) = u;
    } else {
      float4 r = {v[0] + bv, v[1] + bv, v[2] + bv, v[3] + bv};
      *(float4*)((float*)out + ((size_t)b * 512 + o0 + o_loc) * 1024 + n0 + en) = r;
    }
  }
}

// depthwise 5x5 conv + LayerNorm(128) + exact GELU + 1x1(128->2) + tanh -> pos
__global__ __launch_bounds__(128) void offset_kernel(
    const bf16* __restrict__ q, const float* __restrict__ dw_w,
    const float* __restrict__ dw_b, const float* __restrict__ ln_g,
    const float* __restrict__ ln_b, const float* __restrict__ off_w,
    float* __restrict__ pos, float* __restrict__ out_pos, float* __restrict__ out_ref) {
  const int bg = blockIdx.x;  // 0..15
  const int h = blockIdx.y;   // 0..31
  const int c = threadIdx.x;  // 0..127 (channel)
  const int b = bg >> 2, g = bg & 3;
  const bf16* qp = q + ((size_t)b * CDIM + g * GCH + c) * 1024;
  float wgt[25];
#pragma unroll
  for (int i = 0; i < 25; i++) wgt[i] = dw_w[c * 25 + i];
  const float cbias = dw_b[c];
  const float gam = ln_g[c], bet = ln_b[c];
  const float ow0 = off_w[c], ow1 = off_w[GCH + c];
  __shared__ float red[8];
  for (int w = 0; w < 32; w++) {
    float s = cbias;
#pragma unroll
    for (int ky = 0; ky < 5; ky++) {
      const int y = h + ky - 2;
      if (y < 0 || y >= 32) continue;
#pragma unroll
      for (int kx = 0; kx < 5; kx++) {
        const int x = w + kx - 2;
        if (x < 0 || x >= 32) continue;
        s += wgt[ky * 5 + kx] * bf2f(qp[y * 32 + x]);
      }
    }
    float ssum = s, ssq = s * s;
#pragma unroll
    for (int o = 1; o < 64; o <<= 1) {
      ssum += __shfl_xor(ssum, o);
      ssq += __shfl_xor(ssq, o);
    }
    if ((c & 63) == 0) { red[c >> 6] = ssum; red[2 + (c >> 6)] = ssq; }
    __syncthreads();
    const float mu = (red[0] + red[1]) * (1.0f / 128.0f);
    const float var = (red[2] + red[3]) * (1.0f / 128.0f) - mu * mu;
    const float xn = (s - mu) * rsqrtf(var + 1e-5f) * gam + bet;
    const float ge = 0.5f * xn * (1.0f + erff(xn * 0.70710678118654752f));
    float p0 = ow0 * ge, p1 = ow1 * ge;
#pragma unroll
    for (int o = 1; o < 64; o <<= 1) {
      p0 += __shfl_xor(p0, o);
      p1 += __shfl_xor(p1, o);
    }
    if ((c & 63) == 0) { red[4 + (c >> 6)] = p0; red[6 + (c >> 6)] = p1; }
    __syncthreads();
    if (c == 0) {
      const float oy = tanhf(red[4] + red[5]) * 0.0625f;  // (1/32)*2
      const float ox = tanhf(red[6] + red[7]) * 0.0625f;
      const float ry = ((float)h + 0.5f) * (2.0f / 32.0f) - 1.0f;
      const float rx = ((float)w + 0.5f) * (2.0f / 32.0f) - 1.0f;
      const float py = oy + ry, px = ox + rx;
      const size_t idx = (size_t)bg * 1024 + h * 32 + w;
      pos[idx * 2] = py;
      pos[idx * 2 + 1] = px;
      out_pos[idx * 2] = py;
      out_pos[idx * 2 + 1] = px;
      out_ref[idx * 2] = ry;
      out_ref[idx * 2 + 1] = rx;
    }
    __syncthreads();
  }
}

// bilinear grid-sample of x at pos -> xs [16][128][1024]
__global__ __launch_bounds__(256) void sample_kernel(
    const float* __restrict__ x, const float* __restrict__ pos, bf16* __restrict__ xs) {
  const int bg = blockIdx.x, c = blockIdx.y;
  const int b = bg >> 2, g = bg & 3;
  __shared__ float plane[1024];
  const float* xp = x + ((size_t)b * CDIM + g * GCH + c) * 1024;
  for (int i = threadIdx.x; i < 1024; i += 256) plane[i] = xp[i];
  __syncthreads();
  for (int s = threadIdx.x; s < 1024; s += 256) {
    const float py = pos[((size_t)bg * 1024 + s) * 2];
    const float px = pos[((size_t)bg * 1024 + s) * 2 + 1];
    const float gx = (px + 1.0f) * 15.5f;  // align_corners=True, W=32
    const float gy = (py + 1.0f) * 15.5f;
    const float x0f = floorf(gx), y0f = floorf(gy);
    const float wx = gx - x0f, wy = gy - y0f;
    const int ix = (int)x0f, iy = (int)y0f;
    float r = 0.0f;
    const bool vx0 = (ix >= 0) & (ix <= 31), vx1 = (ix + 1 >= 0) & (ix + 1 <= 31);
    const bool vy0 = (iy >= 0) & (iy <= 31), vy1 = (iy + 1 >= 0) & (iy + 1 <= 31);
    if (vy0 && vx0) r += plane[iy * 32 + ix] * (1.0f - wx) * (1.0f - wy);
    if (vy0 && vx1) r += plane[iy * 32 + ix + 1] * wx * (1.0f - wy);
    if (vy1 && vx0) r += plane[(iy + 1) * 32 + ix] * (1.0f - wx) * wy;
    if (vy1 && vx1) r += plane[(iy + 1) * 32 + ix + 1] * wx * wy;
    xs[((size_t)bg * GCH + c) * 1024 + s] = __float2bfloat16(r);
  }
}

// Swapped-operand MFMA attention: 64 queries/block, 4 waves x 16 queries.
// S^T = mfma(A=K, B=Q): D col = query (lane cl), rows = keys -> softmax over
// keys is lane-local (in-lane tree + shfl_xor 16/32). O^T = mfma(A=V^T, B=P^T):
// D col = query again -> rescale/normalize lane-local. P crosses lanes only
// through a per-wave p_lds region (no barrier). 2 barriers/tile (was 4).
__global__ __launch_bounds__(256) void attn_kernel(
    const bf16* __restrict__ q, const bf16* __restrict__ kk,
    const bf16* __restrict__ vv, const float* __restrict__ pos,
    const float* __restrict__ rpe, bf16* __restrict__ ao) {
  __shared__ __align__(16) unsigned char smem[33280];
  unsigned char* k_lds = smem;            // [64 n][64 c] bf16 swz (8K)
  unsigned char* v_lds = smem + 8192;     // [64 c][64 n] bf16 swz (8K)
  unsigned char* p_lds = smem + 16384;    // [64 q][64 n] bf16 swz (8K)
  float* pos_s = (float*)(smem + 24576);         // 128 f32
  unsigned short* rpe_s = (unsigned short*)(smem + 25088);  // 63*63 bf16

  const int bh = blockIdx.y;       // 0..31
  const int m0 = blockIdx.x * 64;  // query tile base
  const int b = bh >> 3, h = bh & 7;
  const int g = h >> 1;
  const int bg = b * 4 + g;
  const int t = threadIdx.x, l = t & 63, w = t >> 6;
  const int rg = l >> 4, cl = l & 15;
  const size_t hbase = ((size_t)b * CDIM + h * 64) * 1024;
  const unsigned short* qu = (const unsigned short*)q;

  for (int i = t; i < 63 * 63; i += 256) rpe_s[i] = f2bu(rpe[h * 3969 + i]);

  // per-lane query
  const int qloc = 16 * w + cl;    // 0..63
  const int qm = m0 + qloc;        // global query index
  const float qy = ((float)(qm >> 5) + 0.5f) * (2.0f / 32.0f) - 1.0f;
  const float qx = ((float)(qm & 31) + 0.5f) * (2.0f / 32.0f) - 1.0f;

  // Q B-frags (persistent): bq[kc] holds Q[32kc+8rg+j][qm]
  bf16x8 bq[2];
#pragma unroll
  for (int kc = 0; kc < 2; kc++) {
    bf16x8 a;
#pragma unroll
    for (int j = 0; j < 8; j++)
      a[j] = (short)qu[hbase + (size_t)(32 * kc + 8 * rg + j) * 1024 + qm];
    bq[kc] = a;
  }

  float rmax = -1e30f, rsum = 0.0f;
  f32x4 oacc[4] = {{0.f,0.f,0.f,0.f},{0.f,0.f,0.f,0.f},
                   {0.f,0.f,0.f,0.f},{0.f,0.f,0.f,0.f}};

  const float* posb = pos + (size_t)bg * 2048;
  const unsigned swl = (unsigned)((cl & 7) << 4);  // lane-row swizzle (rows≡cl mod 16)
  // staging maps
  const int kc2 = (t & 31) * 2;   // K-pack: channel pair
  const int kn8 = (t >> 5) * 8;   // K-pack: n block
  const int vc = t >> 2;          // V copy: row c
  const int vh = (t & 3) * 32;    // V copy: byte offset

  for (int n0 = 0; n0 < 1024; n0 += 64) {
    // ---- stage: K transpose-pack [c][n]->[n][c], V raw [c][n], pos tile ----
    {
      union { uint4 v; unsigned short hw[8]; } r0, r1;
      r0.v = *(const uint4*)(kk + hbase + (size_t)kc2 * 1024 + n0 + kn8);
      r1.v = *(const uint4*)(kk + hbase + (size_t)(kc2 + 1) * 1024 + n0 + kn8);
#pragma unroll
      for (int i = 0; i < 8; i++) {
        const int n = kn8 + i;
        const unsigned v32 = (unsigned)r0.hw[i] | ((unsigned)r1.hw[i] << 16);
        *(unsigned*)(k_lds + n * 128 + ((kc2 * 2) ^ ((n & 7) << 4))) = v32;
      }
      const uint4 s0 = *(const uint4*)(vv + hbase + (size_t)vc * 1024 + n0 + vh / 2);
      const uint4 s1 = *(const uint4*)(vv + hbase + (size_t)vc * 1024 + n0 + vh / 2 + 8);
      *(uint4*)(v_lds + vc * 128 + (vh ^ ((vc & 7) << 4))) = s0;
      *(uint4*)(v_lds + vc * 128 + ((vh + 16) ^ ((vc & 7) << 4))) = s1;
      if (t < 128) pos_s[t] = posb[2 * n0 + t];
    }
    __syncthreads();  // staging visible

    // ---- S^T = K·Q  (8 MFMA): sf[tn] rows=keys 16tn+4rg+r, col=query cl ----
    f32x4 sf[4];
#pragma unroll
    for (int tn = 0; tn < 4; tn++) {
      const int nrow = 16 * tn + cl;
      const bf16x8 a0 = *(const bf16x8*)(k_lds + nrow * 128 + ((16 * rg) ^ swl));
      const bf16x8 a1 = *(const bf16x8*)(k_lds + nrow * 128 + ((64 + 16 * rg) ^ swl));
      f32x4 z = {0.f, 0.f, 0.f, 0.f};
      z = __builtin_amdgcn_mfma_f32_16x16x32_bf16(a0, bq[0], z, 0, 0, 0);
      z = __builtin_amdgcn_mfma_f32_16x16x32_bf16(a1, bq[1], z, 0, 0, 0);
      sf[tn] = z;
    }

    // ---- bias + scale (16 bilinear lookups; query fixed per lane) ----
#pragma unroll
    for (int tn = 0; tn < 4; tn++)
#pragma unroll
      for (int r = 0; r < 4; r++) {
        const int key = 16 * tn + 4 * rg + r;
        const float py = pos_s[2 * key], px = pos_s[2 * key + 1];
        const float gyc = ((qy - py) * 0.5f + 1.0f) * 31.0f;
        const float gxc = ((qx - px) * 0.5f + 1.0f) * 31.0f;
        const float y0f = floorf(gyc), x0f = floorf(gxc);
        const float wy = gyc - y0f, wx = gxc - x0f;
        const int iy = (int)y0f, ix = (int)x0f;
        const bool vy0 = (iy >= 0) & (iy <= 62), vy1 = (iy + 1 >= 0) & (iy + 1 <= 62);
        const bool vx0 = (ix >= 0) & (ix <= 62), vx1 = (ix + 1 >= 0) & (ix + 1 <= 62);
        const int ry0 = iy * 63, ry1 = ry0 + 63;
        float bias = 0.0f;
        if (vy0 && vx0) bias += bfu2f(rpe_s[ry0 + ix]) * (1.0f - wx) * (1.0f - wy);
        if (vy0 && vx1) bias += bfu2f(rpe_s[ry0 + ix + 1]) * wx * (1.0f - wy);
        if (vy1 && vx0) bias += bfu2f(rpe_s[ry1 + ix]) * (1.0f - wx) * wy;
        if (vy1 && vx1) bias += bfu2f(rpe_s[ry1 + ix + 1]) * wx * wy;
        sf[tn][r] = sf[tn][r] * 0.125f + bias;
      }

    // ---- lane-local online softmax over the tile's 64 keys ----
    float tmax = sf[0][0];
#pragma unroll
    for (int tn = 0; tn < 4; tn++)
#pragma unroll
      for (int r = 0; r < 4; r++) tmax = fmaxf(tmax, sf[tn][r]);
    tmax = fmaxf(tmax, __shfl_xor(tmax, 16));
    tmax = fmaxf(tmax, __shfl_xor(tmax, 32));
    const float nmax = fmaxf(rmax, tmax);
    const float corr = __expf(rmax - nmax);
    rmax = nmax;
    float lsum = 0.0f;
    unsigned pw[8];
#pragma unroll
    for (int tn = 0; tn < 4; tn++) {
      const float p0 = __expf(sf[tn][0] - nmax);
      const float p1 = __expf(sf[tn][1] - nmax);
      const float p2 = __expf(sf[tn][2] - nmax);
      const float p3 = __expf(sf[tn][3] - nmax);
      lsum += (p0 + p1) + (p2 + p3);
      pw[2 * tn] = pack2(p0, p1);
      pw[2 * tn + 1] = pack2(p2, p3);
    }
    lsum += __shfl_xor(lsum, 16);
    lsum += __shfl_xor(lsum, 32);
    rsum = rsum * corr + lsum;
#pragma unroll
    for (int tc = 0; tc < 4; tc++) {
      oacc[tc][0] *= corr; oacc[tc][1] *= corr;
      oacc[tc][2] *= corr; oacc[tc][3] *= corr;
    }

    // ---- P^T -> p_lds (per-wave region; no barrier needed) ----
#pragma unroll
    for (int tn = 0; tn < 4; tn++) {
      *(unsigned*)(p_lds + qloc * 128 + ((2 * (16 * tn + 4 * rg)) ^ swl)) = pw[2 * tn];
      *(unsigned*)(p_lds + qloc * 128 + ((2 * (16 * tn + 4 * rg) + 4) ^ swl)) = pw[2 * tn + 1];
    }

    // ---- O^T += V^T · P^T  (8 MFMA) ----
#pragma unroll
    for (int kc = 0; kc < 2; kc++) {
      const bf16x8 pb = *(const bf16x8*)(p_lds + qloc * 128 + ((2 * (32 * kc + 8 * rg)) ^ swl));
#pragma unroll
      for (int tc = 0; tc < 4; tc++) {
        const int crow = 16 * tc + cl;
        const bf16x8 av = *(const bf16x8*)(v_lds + crow * 128 + ((2 * (32 * kc + 8 * rg)) ^ swl));
        oacc[tc] = __builtin_amdgcn_mfma_f32_16x16x32_bf16(av, pb, oacc[tc], 0, 0, 0);
      }
    }
    __syncthreads();  // all reads done before next stage overwrites
  }

  // ---- epilogue: normalize (lane-local), stage O[c][q] f32, store bf16 ----
  const float inv = 1.0f / rsum;
  float* o_st = (float*)smem;  // [64 c][66 stride] f32 (16.9 KB, reuses k/v/p)
#pragma unroll
  for (int tc = 0; tc < 4; tc++)
#pragma unroll
    for (int r = 0; r < 4; r++)
      o_st[(16 * tc + 4 * rg + r) * 66 + qloc] = oacc[tc][r] * inv;
  __syncthreads();
  {
    const int c = t >> 2, mq = (t & 3) * 16;
    unsigned u[8];
#pragma unroll
    for (int i = 0; i < 8; i++)
      u[i] = pack2(o_st[c * 66 + mq + 2 * i], o_st[c * 66 + mq + 2 * i + 1]);
    uint4 o0 = {u[0], u[1], u[2], u[3]};
    uint4 o1 = {u[4], u[5], u[6], u[7]};
    *(uint4*)(ao + hbase + (size_t)c * 1024 + m0 + mq) = o0;
    *(uint4*)(ao + hbase + (size_t)c * 1024 + m0 + mq + 8) = o1;
  }
}

extern "C" void kernel_launch(void* const* d_in, const int* in_sizes, int n_in,
                              void* d_out, int out_size, void* d_ws, size_t ws_size,
                              hipStream_t stream) {
  const float* x    = (const float*)d_in[0];
  const float* w_q  = (const float*)d_in[1];
  const float* b_q  = (const float*)d_in[2];
  const float* w_k  = (const float*)d_in[3];
  const float* b_k  = (const float*)d_in[4];
  const float* w_v  = (const float*)d_in[5];
  const float* b_v  = (const float*)d_in[6];
  const float* w_o  = (const float*)d_in[7];
  const float* b_o  = (const float*)d_in[8];
  const float* dw_w = (const float*)d_in[9];
  const float* dw_b = (const float*)d_in[10];
  const float* ln_g = (const float*)d_in[11];
  const float* ln_b = (const float*)d_in[12];
  const float* off_w= (const float*)d_in[13];
  const float* rpe  = (const float*)d_in[14];

  // Outputs are FLOAT32 (reference returns f32 arrays).
  float* out_y   = (float*)d_out;            // [4,512,32,32]   (2097152 f32)
  float* out_pos = out_y + 2097152;          // [4,4,32,32,2]   (32768 f32)
  float* out_ref = out_pos + 32768;          // [4,4,32,32,2]   (32768 f32)

  // workspace (~18.1 MB): pos f32, then bf16 buffers. x_bf aliases k_ws.
  float* pos_ws = (float*)d_ws;              // 32768 f32
  bf16*  q_ws   = (bf16*)(pos_ws + 32768);   // 2097152 bf16
  bf16*  xs_ws  = q_ws + 2097152;            // 2097152 (reused as ao)
  bf16*  k_ws   = xs_ws + 2097152;           // 2097152 (first used as x_bf)
  bf16*  v_ws   = k_ws + 2097152;            // 2097152
  bf16*  w_bf   = v_ws + 2097152;            // 4*262144 bf16 weights
  bf16*  x_bf   = k_ws;
  bf16*  ao_ws  = xs_ws;

  unsigned short* w_bfu = (unsigned short*)w_bf;

  cvt_kernel<<<dim3(1024, 5), 256, 0, stream>>>(x, w_q, w_k, w_v, w_o,
                                                (unsigned short*)x_bf, w_bfu);
  gemm_kernel<bf16><<<dim3(16, 8, 4), 256, 0, stream>>>(
      w_bfu, b_q, (const unsigned short*)x_bf, q_ws);
  offset_kernel<<<dim3(16, 32), 128, 0, stream>>>(q_ws, dw_w, dw_b, ln_g, ln_b, off_w,
                                                  pos_ws, out_pos, out_ref);
  sample_kernel<<<dim3(16, 128), 256, 0, stream>>>(x, pos_ws, xs_ws);
  gemm_kernel<bf16><<<dim3(16, 8, 4), 256, 0, stream>>>(
      w_bfu + 262144, b_k, (const unsigned short*)xs_ws, k_ws);
  gemm_kernel<bf16><<<dim3(16, 8, 4), 256, 0, stream>>>(
      w_bfu + 2 * 262144, b_v, (const unsigned short*)xs_ws, v_ws);
  attn_kernel<<<dim3(16, 32), 256, 0, stream>>>(q_ws, k_ws, v_ws, pos_ws, rpe, ao_ws);
  gemm_kernel<float><<<dim3(16, 8, 4), 256, 0, stream>>>(
      w_bfu + 3 * 262144, b_o, (const unsigned short*)ao_ws, out_y);
}

// Round 9
// 167.612 us; speedup vs baseline: 10.0515x; 1.4792x over previous
//
#include <hip/hip_runtime.h>
#include <hip/hip_bf16.h>

typedef __hip_bfloat16 bf16;
typedef __attribute__((ext_vector_type(8))) short bf16x8;
typedef __attribute__((ext_vector_type(4))) float f32x4;

#define BDIM 4
#define CDIM 512
#define NHEADS 8
#define NGROUPS 4
#define GCH 128

__device__ __forceinline__ float bf2f(bf16 v) { return __bfloat162float(v); }
__device__ __forceinline__ float bfu2f(unsigned short u) {
  return __uint_as_float(((unsigned)u) << 16);
}
__device__ __forceinline__ unsigned short f2bu(float v) {
  return __hip_bfloat16_raw(__float2bfloat16(v)).x;
}
__device__ __forceinline__ unsigned pack2(float lo, float hi) {
  return (unsigned)f2bu(lo) | ((unsigned)f2bu(hi) << 16);
}

// ---- f32 -> bf16 conversion: x (2M) + 4 weight matrices (256K each) ----
__global__ __launch_bounds__(256) void cvt_kernel(
    const float* __restrict__ x, const float* __restrict__ wq,
    const float* __restrict__ wk, const float* __restrict__ wv,
    const float* __restrict__ wo, unsigned short* __restrict__ x_bf,
    unsigned short* __restrict__ w_bf) {
  const int seg = blockIdx.y;
  const float* src;
  unsigned short* dst;
  int count;
  if (seg == 0) { src = x; dst = x_bf; count = 2097152; }
  else {
    src = (seg == 1 ? wq : seg == 2 ? wk : seg == 3 ? wv : wo);
    dst = w_bf + (seg - 1) * 262144;
    count = 262144;
  }
  const int i = (blockIdx.x * 256 + threadIdx.x) * 8;
  if (i >= count) return;
  const float4 a = *(const float4*)(src + i);
  const float4 b = *(const float4*)(src + i + 4);
  uint4 u;
  u.x = pack2(a.x, a.y);
  u.y = pack2(a.z, a.w);
  u.z = pack2(b.x, b.y);
  u.w = pack2(b.z, b.w);
  *(uint4*)(dst + i) = u;
}

// ---- MFMA GEMM (unchanged; verified) ----
template <typename OutT>
__global__ __launch_bounds__(256) void gemm_kernel(
    const unsigned short* __restrict__ Wb,  // [512][512] bf16
    const float* __restrict__ bias,
    const unsigned short* __restrict__ in,  // [4][512][1024] bf16
    OutT* __restrict__ out) {
  __shared__ __align__(16) unsigned char smem[16384];
  unsigned char* a_lds = smem;         // [64 o][64 c] bf16 swz
  unsigned char* b_lds = smem + 8192;  // [64 n][64 c] bf16 swz
  const int b = blockIdx.z;
  const int o0 = blockIdx.y * 64;
  const int n0 = blockIdx.x * 64;
  const int t = threadIdx.x, l = t & 63, w = t >> 6;
  const int rg = l >> 4, cl = l & 15;
  const int o_base = (w >> 1) * 32, n_base = (w & 1) * 32;
  const unsigned short* inb = in + (size_t)b * 524288;
  const int ao = t >> 2;
  const int ac8 = (t & 3) * 8;
  const int kc2 = (t & 31) * 2;
  const int kn8 = (t >> 5) * 8;

  f32x4 acc[2][2] = {{{0.f,0.f,0.f,0.f},{0.f,0.f,0.f,0.f}},
                     {{0.f,0.f,0.f,0.f},{0.f,0.f,0.f,0.f}}};

  for (int k0 = 0; k0 < 512; k0 += 64) {
    {
      const uint4 wa = *(const uint4*)(Wb + (size_t)(o0 + ao) * 512 + k0 + ac8);
      const uint4 wb2 = *(const uint4*)(Wb + (size_t)(o0 + ao) * 512 + k0 + ac8 + 32);
      const unsigned swo = (unsigned)((ao & 7) << 4);
      *(uint4*)(a_lds + ao * 128 + ((2 * ac8) ^ swo)) = wa;
      *(uint4*)(a_lds + ao * 128 + ((2 * ac8 + 64) ^ swo)) = wb2;
    }
    {
      union { uint4 v; unsigned short hw[8]; } r0, r1;
      r0.v = *(const uint4*)(inb + (size_t)(k0 + kc2) * 1024 + n0 + kn8);
      r1.v = *(const uint4*)(inb + (size_t)(k0 + kc2 + 1) * 1024 + n0 + kn8);
#pragma unroll
      for (int i = 0; i < 8; i++) {
        const int n = kn8 + i;
        const unsigned v32 = (unsigned)r0.hw[i] | ((unsigned)r1.hw[i] << 16);
        *(unsigned*)(b_lds + n * 128 + ((2 * kc2) ^ ((n & 7) << 4))) = v32;
      }
    }
    __syncthreads();
#pragma unroll
    for (int kk = 0; kk < 2; kk++) {
      bf16x8 af[2], bfr[2];
#pragma unroll
      for (int m = 0; m < 2; m++) {
        const int o_loc = o_base + 16 * m + cl;
        af[m] = *(const bf16x8*)(a_lds + o_loc * 128 +
                                 ((64 * kk + 16 * rg) ^ ((o_loc & 7) << 4)));
      }
#pragma unroll
      for (int nn = 0; nn < 2; nn++) {
        const int n_loc = n_base + 16 * nn + cl;
        bfr[nn] = *(const bf16x8*)(b_lds + n_loc * 128 +
                                   ((64 * kk + 16 * rg) ^ ((n_loc & 7) << 4)));
      }
#pragma unroll
      for (int m = 0; m < 2; m++)
#pragma unroll
        for (int nn = 0; nn < 2; nn++)
          acc[m][nn] = __builtin_amdgcn_mfma_f32_16x16x32_bf16(af[m], bfr[nn],
                                                               acc[m][nn], 0, 0, 0);
    }
    __syncthreads();
  }

  float* o_st = (float*)smem;  // [64][64]
#pragma unroll
  for (int m = 0; m < 2; m++)
#pragma unroll
    for (int nn = 0; nn < 2; nn++)
#pragma unroll
      for (int r = 0; r < 4; r++)
        o_st[(o_base + 16 * m + 4 * rg + r) * 64 + n_base + 16 * nn + cl] =
            acc[m][nn][r];
  __syncthreads();
  const int eo = t >> 4;
  const int en = (t & 15) * 4;
#pragma unroll
  for (int pass = 0; pass < 4; pass++) {
    const int o_loc = eo + pass * 16;
    const f32x4 v = *(const f32x4*)(o_st + o_loc * 64 + en);
    const float bv = bias[o0 + o_loc];
    if constexpr (sizeof(OutT) == 2) {
      ushort4 u;
      u.x = f2bu(v[0] + bv);
      u.y = f2bu(v[1] + bv);
      u.z = f2bu(v[2] + bv);
      u.w = f2bu(v[3] + bv);
      *(ushort4*)((bf16*)out + ((size_t)b * 512 + o0 + o_loc) * 1024 + n0 + en) = u;
    } else {
      float4 r = {v[0] + bv, v[1] + bv, v[2] + bv, v[3] + bv};
      *(float4*)((float*)out + ((size_t)b * 512 + o0 + o_loc) * 1024 + n0 + en) = r;
    }
  }
}

// depthwise 5x5 conv + LayerNorm(128) + GELU + 1x1(128->2) + tanh -> pos.
// Round-9 restructure (was latency-bound: 107us, VALUBusy 7%, occ 10%):
//  - stage 5 rows x 128 ch x 36 cols (zero-padded) in LDS ONCE (was 800
//    scalar global loads/thread re-issued across the w loop)
//  - 512 threads: 4 w-slots x 128 channels -> 4-way parallel w processing,
//    18 barriers/block (was 64)
//  - LDS layout [ky][x][c]: conv reads 64 consecutive c = 128B = conflict-free
__global__ __launch_bounds__(512) void offset_kernel(
    const bf16* __restrict__ q, const float* __restrict__ dw_w,
    const float* __restrict__ dw_b, const float* __restrict__ ln_g,
    const float* __restrict__ ln_b, const float* __restrict__ off_w,
    float* __restrict__ pos, float* __restrict__ out_pos, float* __restrict__ out_ref) {
  __shared__ unsigned short q_s[5][36][128];  // 46080 B
  __shared__ float red_a[4][2][2];            // [wslot][half][{sum,sq}]
  __shared__ float red_p[4][2][2];            // [wslot][half][{p0,p1}]
  const int bg = blockIdx.x;  // 0..15
  const int h = blockIdx.y;   // 0..31
  const int b = bg >> 2, g = bg & 3;
  const int t = threadIdx.x;

  // ---- stage: tasks (ky, c); zero-pad OOB rows and edge columns ----
  for (int task = t; task < 640; task += 512) {
    const int ky = task >> 7, c = task & 127;
    const int y = h + ky - 2;
    if (y >= 0 && y < 32) {
      const unsigned short* qrow =
          (const unsigned short*)q + ((size_t)b * CDIM + g * GCH + c) * 1024 + y * 32;
      q_s[ky][0][c] = 0;
      q_s[ky][1][c] = 0;
#pragma unroll
      for (int x8 = 0; x8 < 4; x8++) {
        union { uint4 u; unsigned short s[8]; } vv;
        vv.u = *(const uint4*)(qrow + x8 * 8);
#pragma unroll
        for (int i = 0; i < 8; i++) q_s[ky][2 + x8 * 8 + i][c] = vv.s[i];
      }
      q_s[ky][34][c] = 0;
      q_s[ky][35][c] = 0;
    } else {
#pragma unroll
      for (int xi = 0; xi < 36; xi++) q_s[ky][xi][c] = 0;
    }
  }

  const int wslot = t >> 7;      // 0..3
  const int c = t & 127;         // channel
  const int half = c >> 6;       // which wave within the 128-ch group
  const int lane = t & 63;
  float wgt[25];
#pragma unroll
  for (int i = 0; i < 25; i++) wgt[i] = dw_w[c * 25 + i];
  const float cbias = dw_b[c];
  const float gam = ln_g[c], bet = ln_b[c];
  const float ow0 = off_w[c], ow1 = off_w[GCH + c];
  __syncthreads();

  for (int j = 0; j < 8; j++) {
    const int w = wslot * 8 + j;
    float s = cbias;
#pragma unroll
    for (int ky = 0; ky < 5; ky++)
#pragma unroll
      for (int kx = 0; kx < 5; kx++)
        s += wgt[ky * 5 + kx] * bfu2f(q_s[ky][w + kx][c]);
    float ssum = s, ssq = s * s;
#pragma unroll
    for (int o = 1; o < 64; o <<= 1) {
      ssum += __shfl_xor(ssum, o);
      ssq += __shfl_xor(ssq, o);
    }
    if (lane == 0) { red_a[wslot][half][0] = ssum; red_a[wslot][half][1] = ssq; }
    __syncthreads();
    const float mu = (red_a[wslot][0][0] + red_a[wslot][1][0]) * (1.0f / 128.0f);
    const float var = (red_a[wslot][0][1] + red_a[wslot][1][1]) * (1.0f / 128.0f) - mu * mu;
    const float xn = (s - mu) * rsqrtf(var + 1e-5f) * gam + bet;
    const float ge = 0.5f * xn * (1.0f + erff(xn * 0.70710678118654752f));
    float p0 = ow0 * ge, p1 = ow1 * ge;
#pragma unroll
    for (int o = 1; o < 64; o <<= 1) {
      p0 += __shfl_xor(p0, o);
      p1 += __shfl_xor(p1, o);
    }
    if (lane == 0) { red_p[wslot][half][0] = p0; red_p[wslot][half][1] = p1; }
    __syncthreads();
    if (c == 0) {
      const float oy = tanhf(red_p[wslot][0][0] + red_p[wslot][1][0]) * 0.0625f;
      const float ox = tanhf(red_p[wslot][0][1] + red_p[wslot][1][1]) * 0.0625f;
      const float ry = ((float)h + 0.5f) * (2.0f / 32.0f) - 1.0f;
      const float rx = ((float)w + 0.5f) * (2.0f / 32.0f) - 1.0f;
      const float py = oy + ry, px = ox + rx;
      const size_t idx = (size_t)bg * 1024 + h * 32 + w;
      pos[idx * 2] = py;
      pos[idx * 2 + 1] = px;
      out_pos[idx * 2] = py;
      out_pos[idx * 2 + 1] = px;
      out_ref[idx * 2] = ry;
      out_ref[idx * 2 + 1] = rx;
    }
  }
}

// bilinear grid-sample of x at pos -> xs [16][128][1024]
__global__ __launch_bounds__(256) void sample_kernel(
    const float* __restrict__ x, const float* __restrict__ pos, bf16* __restrict__ xs) {
  const int bg = blockIdx.x, c = blockIdx.y;
  const int b = bg >> 2, g = bg & 3;
  __shared__ float plane[1024];
  const float* xp = x + ((size_t)b * CDIM + g * GCH + c) * 1024;
  for (int i = threadIdx.x; i < 1024; i += 256) plane[i] = xp[i];
  __syncthreads();
  for (int s = threadIdx.x; s < 1024; s += 256) {
    const float py = pos[((size_t)bg * 1024 + s) * 2];
    const float px = pos[((size_t)bg * 1024 + s) * 2 + 1];
    const float gx = (px + 1.0f) * 15.5f;  // align_corners=True, W=32
    const float gy = (py + 1.0f) * 15.5f;
    const float x0f = floorf(gx), y0f = floorf(gy);
    const float wx = gx - x0f, wy = gy - y0f;
    const int ix = (int)x0f, iy = (int)y0f;
    float r = 0.0f;
    const bool vx0 = (ix >= 0) & (ix <= 31), vx1 = (ix + 1 >= 0) & (ix + 1 <= 31);
    const bool vy0 = (iy >= 0) & (iy <= 31), vy1 = (iy + 1 >= 0) & (iy + 1 <= 31);
    if (vy0 && vx0) r += plane[iy * 32 + ix] * (1.0f - wx) * (1.0f - wy);
    if (vy0 && vx1) r += plane[iy * 32 + ix + 1] * wx * (1.0f - wy);
    if (vy1 && vx0) r += plane[(iy + 1) * 32 + ix] * (1.0f - wx) * wy;
    if (vy1 && vx1) r += plane[(iy + 1) * 32 + ix + 1] * wx * wy;
    xs[((size_t)bg * GCH + c) * 1024 + s] = __float2bfloat16(r);
  }
}

// Swapped-operand MFMA attention (unchanged from round 8; verified).
__global__ __launch_bounds__(256) void attn_kernel(
    const bf16* __restrict__ q, const bf16* __restrict__ kk,
    const bf16* __restrict__ vv, const float* __restrict__ pos,
    const float* __restrict__ rpe, bf16* __restrict__ ao) {
  __shared__ __align__(16) unsigned char smem[33280];
  unsigned char* k_lds = smem;            // [64 n][64 c] bf16 swz (8K)
  unsigned char* v_lds = smem + 8192;     // [64 c][64 n] bf16 swz (8K)
  unsigned char* p_lds = smem + 16384;    // [64 q][64 n] bf16 swz (8K)
  float* pos_s = (float*)(smem + 24576);         // 128 f32
  unsigned short* rpe_s = (unsigned short*)(smem + 25088);  // 63*63 bf16

  const int bh = blockIdx.y;       // 0..31
  const int m0 = blockIdx.x * 64;  // query tile base
  const int b = bh >> 3, h = bh & 7;
  const int g = h >> 1;
  const int bg = b * 4 + g;
  const int t = threadIdx.x, l = t & 63, w = t >> 6;
  const int rg = l >> 4, cl = l & 15;
  const size_t hbase = ((size_t)b * CDIM + h * 64) * 1024;
  const unsigned short* qu = (const unsigned short*)q;

  for (int i = t; i < 63 * 63; i += 256) rpe_s[i] = f2bu(rpe[h * 3969 + i]);

  const int qloc = 16 * w + cl;    // 0..63
  const int qm = m0 + qloc;        // global query index
  const float qy = ((float)(qm >> 5) + 0.5f) * (2.0f / 32.0f) - 1.0f;
  const float qx = ((float)(qm & 31) + 0.5f) * (2.0f / 32.0f) - 1.0f;

  bf16x8 bq[2];
#pragma unroll
  for (int kc = 0; kc < 2; kc++) {
    bf16x8 a;
#pragma unroll
    for (int j = 0; j < 8; j++)
      a[j] = (short)qu[hbase + (size_t)(32 * kc + 8 * rg + j) * 1024 + qm];
    bq[kc] = a;
  }

  float rmax = -1e30f, rsum = 0.0f;
  f32x4 oacc[4] = {{0.f,0.f,0.f,0.f},{0.f,0.f,0.f,0.f},
                   {0.f,0.f,0.f,0.f},{0.f,0.f,0.f,0.f}};

  const float* posb = pos + (size_t)bg * 2048;
  const unsigned swl = (unsigned)((cl & 7) << 4);
  const int kc2 = (t & 31) * 2;
  const int kn8 = (t >> 5) * 8;
  const int vc = t >> 2;
  const int vh = (t & 3) * 32;

  for (int n0 = 0; n0 < 1024; n0 += 64) {
    {
      union { uint4 v; unsigned short hw[8]; } r0, r1;
      r0.v = *(const uint4*)(kk + hbase + (size_t)kc2 * 1024 + n0 + kn8);
      r1.v = *(const uint4*)(kk + hbase + (size_t)(kc2 + 1) * 1024 + n0 + kn8);
#pragma unroll
      for (int i = 0; i < 8; i++) {
        const int n = kn8 + i;
        const unsigned v32 = (unsigned)r0.hw[i] | ((unsigned)r1.hw[i] << 16);
        *(unsigned*)(k_lds + n * 128 + ((kc2 * 2) ^ ((n & 7) << 4))) = v32;
      }
      const uint4 s0 = *(const uint4*)(vv + hbase + (size_t)vc * 1024 + n0 + vh / 2);
      const uint4 s1 = *(const uint4*)(vv + hbase + (size_t)vc * 1024 + n0 + vh / 2 + 8);
      *(uint4*)(v_lds + vc * 128 + (vh ^ ((vc & 7) << 4))) = s0;
      *(uint4*)(v_lds + vc * 128 + ((vh + 16) ^ ((vc & 7) << 4))) = s1;
      if (t < 128) pos_s[t] = posb[2 * n0 + t];
    }
    __syncthreads();

    f32x4 sf[4];
#pragma unroll
    for (int tn = 0; tn < 4; tn++) {
      const int nrow = 16 * tn + cl;
      const bf16x8 a0 = *(const bf16x8*)(k_lds + nrow * 128 + ((16 * rg) ^ swl));
      const bf16x8 a1 = *(const bf16x8*)(k_lds + nrow * 128 + ((64 + 16 * rg) ^ swl));
      f32x4 z = {0.f, 0.f, 0.f, 0.f};
      z = __builtin_amdgcn_mfma_f32_16x16x32_bf16(a0, bq[0], z, 0, 0, 0);
      z = __builtin_amdgcn_mfma_f32_16x16x32_bf16(a1, bq[1], z, 0, 0, 0);
      sf[tn] = z;
    }

#pragma unroll
    for (int tn = 0; tn < 4; tn++)
#pragma unroll
      for (int r = 0; r < 4; r++) {
        const int key = 16 * tn + 4 * rg + r;
        const float py = pos_s[2 * key], px = pos_s[2 * key + 1];
        const float gyc = ((qy - py) * 0.5f + 1.0f) * 31.0f;
        const float gxc = ((qx - px) * 0.5f + 1.0f) * 31.0f;
        const float y0f = floorf(gyc), x0f = floorf(gxc);
        const float wy = gyc - y0f, wx = gxc - x0f;
        const int iy = (int)y0f, ix = (int)x0f;
        const bool vy0 = (iy >= 0) & (iy <= 62), vy1 = (iy + 1 >= 0) & (iy + 1 <= 62);
        const bool vx0 = (ix >= 0) & (ix <= 62), vx1 = (ix + 1 >= 0) & (ix + 1 <= 62);
        const int ry0 = iy * 63, ry1 = ry0 + 63;
        float bias = 0.0f;
        if (vy0 && vx0) bias += bfu2f(rpe_s[ry0 + ix]) * (1.0f - wx) * (1.0f - wy);
        if (vy0 && vx1) bias += bfu2f(rpe_s[ry0 + ix + 1]) * wx * (1.0f - wy);
        if (vy1 && vx0) bias += bfu2f(rpe_s[ry1 + ix]) * (1.0f - wx) * wy;
        if (vy1 && vx1) bias += bfu2f(rpe_s[ry1 + ix + 1]) * wx * wy;
        sf[tn][r] = sf[tn][r] * 0.125f + bias;
      }

    float tmax = sf[0][0];
#pragma unroll
    for (int tn = 0; tn < 4; tn++)
#pragma unroll
      for (int r = 0; r < 4; r++) tmax = fmaxf(tmax, sf[tn][r]);
    tmax = fmaxf(tmax, __shfl_xor(tmax, 16));
    tmax = fmaxf(tmax, __shfl_xor(tmax, 32));
    const float nmax = fmaxf(rmax, tmax);
    const float corr = __expf(rmax - nmax);
    rmax = nmax;
    float lsum = 0.0f;
    unsigned pw[8];
#pragma unroll
    for (int tn = 0; tn < 4; tn++) {
      const float p0 = __expf(sf[tn][0] - nmax);
      const float p1 = __expf(sf[tn][1] - nmax);
      const float p2 = __expf(sf[tn][2] - nmax);
      const float p3 = __expf(sf[tn][3] - nmax);
      lsum += (p0 + p1) + (p2 + p3);
      pw[2 * tn] = pack2(p0, p1);
      pw[2 * tn + 1] = pack2(p2, p3);
    }
    lsum += __shfl_xor(lsum, 16);
    lsum += __shfl_xor(lsum, 32);
    rsum = rsum * corr + lsum;
#pragma unroll
    for (int tc = 0; tc < 4; tc++) {
      oacc[tc][0] *= corr; oacc[tc][1] *= corr;
      oacc[tc][2] *= corr; oacc[tc][3] *= corr;
    }

#pragma unroll
    for (int tn = 0; tn < 4; tn++) {
      *(unsigned*)(p_lds + qloc * 128 + ((2 * (16 * tn + 4 * rg)) ^ swl)) = pw[2 * tn];
      *(unsigned*)(p_lds + qloc * 128 + ((2 * (16 * tn + 4 * rg) + 4) ^ swl)) = pw[2 * tn + 1];
    }

#pragma unroll
    for (int kc = 0; kc < 2; kc++) {
      const bf16x8 pb = *(const bf16x8*)(p_lds + qloc * 128 + ((2 * (32 * kc + 8 * rg)) ^ swl));
#pragma unroll
      for (int tc = 0; tc < 4; tc++) {
        const int crow = 16 * tc + cl;
        const bf16x8 av = *(const bf16x8*)(v_lds + crow * 128 + ((2 * (32 * kc + 8 * rg)) ^ swl));
        oacc[tc] = __builtin_amdgcn_mfma_f32_16x16x32_bf16(av, pb, oacc[tc], 0, 0, 0);
      }
    }
    __syncthreads();
  }

  const float inv = 1.0f / rsum;
  float* o_st = (float*)smem;  // [64 c][66 stride] f32
#pragma unroll
  for (int tc = 0; tc < 4; tc++)
#pragma unroll
    for (int r = 0; r < 4; r++)
      o_st[(16 * tc + 4 * rg + r) * 66 + qloc] = oacc[tc][r] * inv;
  __syncthreads();
  {
    const int c = t >> 2, mq = (t & 3) * 16;
    unsigned u[8];
#pragma unroll
    for (int i = 0; i < 8; i++)
      u[i] = pack2(o_st[c * 66 + mq + 2 * i], o_st[c * 66 + mq + 2 * i + 1]);
    uint4 o0 = {u[0], u[1], u[2], u[3]};
    uint4 o1 = {u[4], u[5], u[6], u[7]};
    *(uint4*)(ao + hbase + (size_t)c * 1024 + m0 + mq) = o0;
    *(uint4*)(ao + hbase + (size_t)c * 1024 + m0 + mq + 8) = o1;
  }
}

extern "C" void kernel_launch(void* const* d_in, const int* in_sizes, int n_in,
                              void* d_out, int out_size, void* d_ws, size_t ws_size,
                              hipStream_t stream) {
  const float* x    = (const float*)d_in[0];
  const float* w_q  = (const float*)d_in[1];
  const float* b_q  = (const float*)d_in[2];
  const float* w_k  = (const float*)d_in[3];
  const float* b_k  = (const float*)d_in[4];
  const float* w_v  = (const float*)d_in[5];
  const float* b_v  = (const float*)d_in[6];
  const float* w_o  = (const float*)d_in[7];
  const float* b_o  = (const float*)d_in[8];
  const float* dw_w = (const float*)d_in[9];
  const float* dw_b = (const float*)d_in[10];
  const float* ln_g = (const float*)d_in[11];
  const float* ln_b = (const float*)d_in[12];
  const float* off_w= (const float*)d_in[13];
  const float* rpe  = (const float*)d_in[14];

  // Outputs are FLOAT32 (reference returns f32 arrays).
  float* out_y   = (float*)d_out;            // [4,512,32,32]   (2097152 f32)
  float* out_pos = out_y + 2097152;          // [4,4,32,32,2]   (32768 f32)
  float* out_ref = out_pos + 32768;          // [4,4,32,32,2]   (32768 f32)

  // workspace (~18.1 MB): pos f32, then bf16 buffers. x_bf aliases k_ws.
  float* pos_ws = (float*)d_ws;              // 32768 f32
  bf16*  q_ws   = (bf16*)(pos_ws + 32768);   // 2097152 bf16
  bf16*  xs_ws  = q_ws + 2097152;            // 2097152 (reused as ao)
  bf16*  k_ws   = xs_ws + 2097152;           // 2097152 (first used as x_bf)
  bf16*  v_ws   = k_ws + 2097152;            // 2097152
  bf16*  w_bf   = v_ws + 2097152;            // 4*262144 bf16 weights
  bf16*  x_bf   = k_ws;
  bf16*  ao_ws  = xs_ws;

  unsigned short* w_bfu = (unsigned short*)w_bf;

  cvt_kernel<<<dim3(1024, 5), 256, 0, stream>>>(x, w_q, w_k, w_v, w_o,
                                                (unsigned short*)x_bf, w_bfu);
  gemm_kernel<bf16><<<dim3(16, 8, 4), 256, 0, stream>>>(
      w_bfu, b_q, (const unsigned short*)x_bf, q_ws);
  offset_kernel<<<dim3(16, 32), 512, 0, stream>>>(q_ws, dw_w, dw_b, ln_g, ln_b, off_w,
                                                  pos_ws, out_pos, out_ref);
  sample_kernel<<<dim3(16, 128), 256, 0, stream>>>(x, pos_ws, xs_ws);
  gemm_kernel<bf16><<<dim3(16, 8, 4), 256, 0, stream>>>(
      w_bfu + 262144, b_k, (const unsigned short*)xs_ws, k_ws);
  gemm_kernel<bf16><<<dim3(16, 8, 4), 256, 0, stream>>>(
      w_bfu + 2 * 262144, b_v, (const unsigned short*)xs_ws, v_ws);
  attn_kernel<<<dim3(16, 32), 256, 0, stream>>>(q_ws, k_ws, v_ws, pos_ws, rpe, ao_ws);
  gemm_kernel<float><<<dim3(16, 8, 4), 256, 0, stream>>>(
      w_bfu + 3 * 262144, b_o, (const unsigned short*)ao_ws, out_y);
}

// Round 10
// 118.268 us; speedup vs baseline: 14.2452x; 1.4172x over previous
//
#include <hip/hip_runtime.h>
#include <hip/hip_bf16.h>

typedef __hip_bfloat16 bf16;
typedef __attribute__((ext_vector_type(8))) short bf16x8;
typedef __attribute__((ext_vector_type(4))) float f32x4;

#define BDIM 4
#define CDIM 512
#define NHEADS 8
#define NGROUPS 4
#define GCH 128

__device__ __forceinline__ float bf2f(bf16 v) { return __bfloat162float(v); }
__device__ __forceinline__ float bfu2f(unsigned short u) {
  return __uint_as_float(((unsigned)u) << 16);
}
__device__ __forceinline__ unsigned short f2bu(float v) {
  return __hip_bfloat16_raw(__float2bfloat16(v)).x;
}
__device__ __forceinline__ unsigned pack2(float lo, float hi) {
  return (unsigned)f2bu(lo) | ((unsigned)f2bu(hi) << 16);
}

// ---- f32 -> bf16 conversion: x (2M) + 4 weight matrices (256K each) ----
__global__ __launch_bounds__(256) void cvt_kernel(
    const float* __restrict__ x, const float* __restrict__ wq,
    const float* __restrict__ wk, const float* __restrict__ wv,
    const float* __restrict__ wo, unsigned short* __restrict__ x_bf,
    unsigned short* __restrict__ w_bf) {
  const int seg = blockIdx.y;
  const float* src;
  unsigned short* dst;
  int count;
  if (seg == 0) { src = x; dst = x_bf; count = 2097152; }
  else {
    src = (seg == 1 ? wq : seg == 2 ? wk : seg == 3 ? wv : wo);
    dst = w_bf + (seg - 1) * 262144;
    count = 262144;
  }
  const int i = (blockIdx.x * 256 + threadIdx.x) * 8;
  if (i >= count) return;
  const float4 a = *(const float4*)(src + i);
  const float4 b = *(const float4*)(src + i + 4);
  uint4 u;
  u.x = pack2(a.x, a.y);
  u.y = pack2(a.z, a.w);
  u.z = pack2(b.x, b.y);
  u.w = pack2(b.z, b.w);
  *(uint4*)(dst + i) = u;
}

// ---- MFMA GEMM (unchanged; verified) ----
template <typename OutT>
__global__ __launch_bounds__(256) void gemm_kernel(
    const unsigned short* __restrict__ Wb,  // [512][512] bf16
    const float* __restrict__ bias,
    const unsigned short* __restrict__ in,  // [4][512][1024] bf16
    OutT* __restrict__ out) {
  __shared__ __align__(16) unsigned char smem[16384];
  unsigned char* a_lds = smem;         // [64 o][64 c] bf16 swz
  unsigned char* b_lds = smem + 8192;  // [64 n][64 c] bf16 swz
  const int b = blockIdx.z;
  const int o0 = blockIdx.y * 64;
  const int n0 = blockIdx.x * 64;
  const int t = threadIdx.x, l = t & 63, w = t >> 6;
  const int rg = l >> 4, cl = l & 15;
  const int o_base = (w >> 1) * 32, n_base = (w & 1) * 32;
  const unsigned short* inb = in + (size_t)b * 524288;
  const int ao = t >> 2;
  const int ac8 = (t & 3) * 8;
  const int kc2 = (t & 31) * 2;
  const int kn8 = (t >> 5) * 8;

  f32x4 acc[2][2] = {{{0.f,0.f,0.f,0.f},{0.f,0.f,0.f,0.f}},
                     {{0.f,0.f,0.f,0.f},{0.f,0.f,0.f,0.f}}};

  for (int k0 = 0; k0 < 512; k0 += 64) {
    {
      const uint4 wa = *(const uint4*)(Wb + (size_t)(o0 + ao) * 512 + k0 + ac8);
      const uint4 wb2 = *(const uint4*)(Wb + (size_t)(o0 + ao) * 512 + k0 + ac8 + 32);
      const unsigned swo = (unsigned)((ao & 7) << 4);
      *(uint4*)(a_lds + ao * 128 + ((2 * ac8) ^ swo)) = wa;
      *(uint4*)(a_lds + ao * 128 + ((2 * ac8 + 64) ^ swo)) = wb2;
    }
    {
      union { uint4 v; unsigned short hw[8]; } r0, r1;
      r0.v = *(const uint4*)(inb + (size_t)(k0 + kc2) * 1024 + n0 + kn8);
      r1.v = *(const uint4*)(inb + (size_t)(k0 + kc2 + 1) * 1024 + n0 + kn8);
#pragma unroll
      for (int i = 0; i < 8; i++) {
        const int n = kn8 + i;
        const unsigned v32 = (unsigned)r0.hw[i] | ((unsigned)r1.hw[i] << 16);
        *(unsigned*)(b_lds + n * 128 + ((2 * kc2) ^ ((n & 7) << 4))) = v32;
      }
    }
    __syncthreads();
#pragma unroll
    for (int kk = 0; kk < 2; kk++) {
      bf16x8 af[2], bfr[2];
#pragma unroll
      for (int m = 0; m < 2; m++) {
        const int o_loc = o_base + 16 * m + cl;
        af[m] = *(const bf16x8*)(a_lds + o_loc * 128 +
                                 ((64 * kk + 16 * rg) ^ ((o_loc & 7) << 4)));
      }
#pragma unroll
      for (int nn = 0; nn < 2; nn++) {
        const int n_loc = n_base + 16 * nn + cl;
        bfr[nn] = *(const bf16x8*)(b_lds + n_loc * 128 +
                                   ((64 * kk + 16 * rg) ^ ((n_loc & 7) << 4)));
      }
#pragma unroll
      for (int m = 0; m < 2; m++)
#pragma unroll
        for (int nn = 0; nn < 2; nn++)
          acc[m][nn] = __builtin_amdgcn_mfma_f32_16x16x32_bf16(af[m], bfr[nn],
                                                               acc[m][nn], 0, 0, 0);
    }
    __syncthreads();
  }

  float* o_st = (float*)smem;  // [64][64]
#pragma unroll
  for (int m = 0; m < 2; m++)
#pragma unroll
    for (int nn = 0; nn < 2; nn++)
#pragma unroll
      for (int r = 0; r < 4; r++)
        o_st[(o_base + 16 * m + 4 * rg + r) * 64 + n_base + 16 * nn + cl] =
            acc[m][nn][r];
  __syncthreads();
  const int eo = t >> 4;
  const int en = (t & 15) * 4;
#pragma unroll
  for (int pass = 0; pass < 4; pass++) {
    const int o_loc = eo + pass * 16;
    const f32x4 v = *(const f32x4*)(o_st + o_loc * 64 + en);
    const float bv = bias[o0 + o_loc];
    if constexpr (sizeof(OutT) == 2) {
      ushort4 u;
      u.x = f2bu(v[0] + bv);
      u.y = f2bu(v[1] + bv);
      u.z = f2bu(v[2] + bv);
      u.w = f2bu(v[3] + bv);
      *(ushort4*)((bf16*)out + ((size_t)b * 512 + o0 + o_loc) * 1024 + n0 + en) = u;
    } else {
      float4 r = {v[0] + bv, v[1] + bv, v[2] + bv, v[3] + bv};
      *(float4*)((float*)out + ((size_t)b * 512 + o0 + o_loc) * 1024 + n0 + en) = r;
    }
  }
}

// depthwise 5x5 conv + LayerNorm(128) + GELU + 1x1(128->2) + tanh -> pos.
// (round-9 restructure; verified)
__global__ __launch_bounds__(512) void offset_kernel(
    const bf16* __restrict__ q, const float* __restrict__ dw_w,
    const float* __restrict__ dw_b, const float* __restrict__ ln_g,
    const float* __restrict__ ln_b, const float* __restrict__ off_w,
    float* __restrict__ pos, float* __restrict__ out_pos, float* __restrict__ out_ref) {
  __shared__ unsigned short q_s[5][36][128];  // 46080 B
  __shared__ float red_a[4][2][2];            // [wslot][half][{sum,sq}]
  __shared__ float red_p[4][2][2];            // [wslot][half][{p0,p1}]
  const int bg = blockIdx.x;  // 0..15
  const int h = blockIdx.y;   // 0..31
  const int b = bg >> 2, g = bg & 3;
  const int t = threadIdx.x;

  for (int task = t; task < 640; task += 512) {
    const int ky = task >> 7, c = task & 127;
    const int y = h + ky - 2;
    if (y >= 0 && y < 32) {
      const unsigned short* qrow =
          (const unsigned short*)q + ((size_t)b * CDIM + g * GCH + c) * 1024 + y * 32;
      q_s[ky][0][c] = 0;
      q_s[ky][1][c] = 0;
#pragma unroll
      for (int x8 = 0; x8 < 4; x8++) {
        union { uint4 u; unsigned short s[8]; } vv;
        vv.u = *(const uint4*)(qrow + x8 * 8);
#pragma unroll
        for (int i = 0; i < 8; i++) q_s[ky][2 + x8 * 8 + i][c] = vv.s[i];
      }
      q_s[ky][34][c] = 0;
      q_s[ky][35][c] = 0;
    } else {
#pragma unroll
      for (int xi = 0; xi < 36; xi++) q_s[ky][xi][c] = 0;
    }
  }

  const int wslot = t >> 7;      // 0..3
  const int c = t & 127;         // channel
  const int half = c >> 6;
  const int lane = t & 63;
  float wgt[25];
#pragma unroll
  for (int i = 0; i < 25; i++) wgt[i] = dw_w[c * 25 + i];
  const float cbias = dw_b[c];
  const float gam = ln_g[c], bet = ln_b[c];
  const float ow0 = off_w[c], ow1 = off_w[GCH + c];
  __syncthreads();

  for (int j = 0; j < 8; j++) {
    const int w = wslot * 8 + j;
    float s = cbias;
#pragma unroll
    for (int ky = 0; ky < 5; ky++)
#pragma unroll
      for (int kx = 0; kx < 5; kx++)
        s += wgt[ky * 5 + kx] * bfu2f(q_s[ky][w + kx][c]);
    float ssum = s, ssq = s * s;
#pragma unroll
    for (int o = 1; o < 64; o <<= 1) {
      ssum += __shfl_xor(ssum, o);
      ssq += __shfl_xor(ssq, o);
    }
    if (lane == 0) { red_a[wslot][half][0] = ssum; red_a[wslot][half][1] = ssq; }
    __syncthreads();
    const float mu = (red_a[wslot][0][0] + red_a[wslot][1][0]) * (1.0f / 128.0f);
    const float var = (red_a[wslot][0][1] + red_a[wslot][1][1]) * (1.0f / 128.0f) - mu * mu;
    const float xn = (s - mu) * rsqrtf(var + 1e-5f) * gam + bet;
    const float ge = 0.5f * xn * (1.0f + erff(xn * 0.70710678118654752f));
    float p0 = ow0 * ge, p1 = ow1 * ge;
#pragma unroll
    for (int o = 1; o < 64; o <<= 1) {
      p0 += __shfl_xor(p0, o);
      p1 += __shfl_xor(p1, o);
    }
    if (lane == 0) { red_p[wslot][half][0] = p0; red_p[wslot][half][1] = p1; }
    __syncthreads();
    if (c == 0) {
      const float oy = tanhf(red_p[wslot][0][0] + red_p[wslot][1][0]) * 0.0625f;
      const float ox = tanhf(red_p[wslot][0][1] + red_p[wslot][1][1]) * 0.0625f;
      const float ry = ((float)h + 0.5f) * (2.0f / 32.0f) - 1.0f;
      const float rx = ((float)w + 0.5f) * (2.0f / 32.0f) - 1.0f;
      const float py = oy + ry, px = ox + rx;
      const size_t idx = (size_t)bg * 1024 + h * 32 + w;
      pos[idx * 2] = py;
      pos[idx * 2 + 1] = px;
      out_pos[idx * 2] = py;
      out_pos[idx * 2 + 1] = px;
      out_ref[idx * 2] = ry;
      out_ref[idx * 2 + 1] = rx;
    }
  }
}

// bilinear grid-sample of x at pos -> xs [16][128][1024]
__global__ __launch_bounds__(256) void sample_kernel(
    const float* __restrict__ x, const float* __restrict__ pos, bf16* __restrict__ xs) {
  const int bg = blockIdx.x, c = blockIdx.y;
  const int b = bg >> 2, g = bg & 3;
  __shared__ float plane[1024];
  const float* xp = x + ((size_t)b * CDIM + g * GCH + c) * 1024;
  for (int i = threadIdx.x; i < 1024; i += 256) plane[i] = xp[i];
  __syncthreads();
  for (int s = threadIdx.x; s < 1024; s += 256) {
    const float py = pos[((size_t)bg * 1024 + s) * 2];
    const float px = pos[((size_t)bg * 1024 + s) * 2 + 1];
    const float gx = (px + 1.0f) * 15.5f;  // align_corners=True, W=32
    const float gy = (py + 1.0f) * 15.5f;
    const float x0f = floorf(gx), y0f = floorf(gy);
    const float wx = gx - x0f, wy = gy - y0f;
    const int ix = (int)x0f, iy = (int)y0f;
    float r = 0.0f;
    const bool vx0 = (ix >= 0) & (ix <= 31), vx1 = (ix + 1 >= 0) & (ix + 1 <= 31);
    const bool vy0 = (iy >= 0) & (iy <= 31), vy1 = (iy + 1 >= 0) & (iy + 1 <= 31);
    if (vy0 && vx0) r += plane[iy * 32 + ix] * (1.0f - wx) * (1.0f - wy);
    if (vy0 && vx1) r += plane[iy * 32 + ix + 1] * wx * (1.0f - wy);
    if (vy1 && vx0) r += plane[(iy + 1) * 32 + ix] * (1.0f - wx) * wy;
    if (vy1 && vx1) r += plane[(iy + 1) * 32 + ix + 1] * wx * wy;
    xs[((size_t)bg * GCH + c) * 1024 + s] = __float2bfloat16(r);
  }
}

// Swapped-operand MFMA attention, split-KV x2.
// 512 threads = 8 waves: wq = w&3 owns 16 queries, half = w>>2 owns 512 keys.
// Per half: 8 KV tiles (was 16) -> half the serial critical path; 16 waves/CU.
// Bias: zero-padded f32 rpe table [65][66] (no bounds masks) + affine pos
// (a = 31 - 15.5*pos staged; gyc = 15.5*qy + a[key]).
// Final: 2-way online-softmax state combine in LDS.
__global__ __launch_bounds__(512) void attn_kernel(
    const bf16* __restrict__ q, const bf16* __restrict__ kk,
    const bf16* __restrict__ vv, const float* __restrict__ pos,
    const float* __restrict__ rpe, bf16* __restrict__ ao) {
  __shared__ __align__(16) unsigned char smem[68384];
  // [0,16384): K tiles (half*8192) | [16384,32768): V | [32768,49152): P
  // [49152,66336): rpe_f [65][66] f32 (+pad) | [66336,67360): pos_a [2][128]
  // [67360,67872): m_x | [67872,68384): s_x
  float* rpe_f = (float*)(smem + 49152);
  float* m_x = (float*)(smem + 67360);
  float* s_x = (float*)(smem + 67872);

  const int bh = blockIdx.y;       // 0..31
  const int m0 = blockIdx.x * 64;  // query tile base
  const int b = bh >> 3, h = bh & 7;
  const int g = h >> 1;
  const int bg = b * 4 + g;
  const int t = threadIdx.x, l = t & 63, w = t >> 6;
  const int wq = w & 3, half = w >> 2;
  const int rg = l >> 4, cl = l & 15;
  const int t2 = t & 255;          // within-half thread id
  const size_t hbase = ((size_t)b * CDIM + h * 64) * 1024;
  const unsigned short* qu = (const unsigned short*)q;

  unsigned char* k_base = smem + half * 8192;
  unsigned char* v_base = smem + 16384 + half * 8192;
  unsigned char* p_base = smem + 32768 + half * 8192;
  float* pos_a = (float*)(smem + 66336) + half * 128;

  // stage padded rpe table (f32, zero border; iy/ix in [-1,63) map to +1)
  for (int i = t; i < 65 * 66; i += 512) {
    const int y = i / 66, x = i - y * 66;
    float v = 0.0f;
    if (y >= 1 && y <= 63 && x >= 1 && x <= 63)
      v = rpe[h * 3969 + (y - 1) * 63 + (x - 1)];
    rpe_f[i] = v;
  }

  // per-lane query
  const int qloc = 16 * wq + cl;   // 0..63
  const int qm = m0 + qloc;
  const float qy15 = 15.5f * (((float)(qm >> 5) + 0.5f) * (2.0f / 32.0f) - 1.0f);
  const float qx15 = 15.5f * (((float)(qm & 31) + 0.5f) * (2.0f / 32.0f) - 1.0f);

  // Q B-frags (persistent)
  bf16x8 bq[2];
#pragma unroll
  for (int kc = 0; kc < 2; kc++) {
    bf16x8 a;
#pragma unroll
    for (int j = 0; j < 8; j++)
      a[j] = (short)qu[hbase + (size_t)(32 * kc + 8 * rg + j) * 1024 + qm];
    bq[kc] = a;
  }

  float rmax = -1e30f, rsum = 0.0f;
  f32x4 oacc[4] = {{0.f,0.f,0.f,0.f},{0.f,0.f,0.f,0.f},
                   {0.f,0.f,0.f,0.f},{0.f,0.f,0.f,0.f}};

  const float* posb = pos + (size_t)bg * 2048;
  const unsigned swl = (unsigned)((cl & 7) << 4);
  const int kc2 = (t2 & 31) * 2;
  const int kn8 = (t2 >> 5) * 8;
  const int vc = t2 >> 2;
  const int vh = (t2 & 3) * 32;

  for (int tile = 0; tile < 8; tile++) {
    const int n0 = half * 512 + tile * 64;
    // ---- stage (each half's 256 threads stage its own tile) ----
    {
      union { uint4 v; unsigned short hw[8]; } r0, r1;
      r0.v = *(const uint4*)(kk + hbase + (size_t)kc2 * 1024 + n0 + kn8);
      r1.v = *(const uint4*)(kk + hbase + (size_t)(kc2 + 1) * 1024 + n0 + kn8);
#pragma unroll
      for (int i = 0; i < 8; i++) {
        const int n = kn8 + i;
        const unsigned v32 = (unsigned)r0.hw[i] | ((unsigned)r1.hw[i] << 16);
        *(unsigned*)(k_base + n * 128 + ((kc2 * 2) ^ ((n & 7) << 4))) = v32;
      }
      const uint4 s0 = *(const uint4*)(vv + hbase + (size_t)vc * 1024 + n0 + vh / 2);
      const uint4 s1 = *(const uint4*)(vv + hbase + (size_t)vc * 1024 + n0 + vh / 2 + 8);
      *(uint4*)(v_base + vc * 128 + (vh ^ ((vc & 7) << 4))) = s0;
      *(uint4*)(v_base + vc * 128 + ((vh + 16) ^ ((vc & 7) << 4))) = s1;
      if (t2 < 128) pos_a[t2] = 31.0f - 15.5f * posb[2 * n0 + t2];
    }
    __syncthreads();

    // ---- S^T = K·Q (8 MFMA) ----
    f32x4 sf[4];
#pragma unroll
    for (int tn = 0; tn < 4; tn++) {
      const int nrow = 16 * tn + cl;
      const bf16x8 a0 = *(const bf16x8*)(k_base + nrow * 128 + ((16 * rg) ^ swl));
      const bf16x8 a1 = *(const bf16x8*)(k_base + nrow * 128 + ((64 + 16 * rg) ^ swl));
      f32x4 z = {0.f, 0.f, 0.f, 0.f};
      z = __builtin_amdgcn_mfma_f32_16x16x32_bf16(a0, bq[0], z, 0, 0, 0);
      z = __builtin_amdgcn_mfma_f32_16x16x32_bf16(a1, bq[1], z, 0, 0, 0);
      sf[tn] = z;
    }

    // ---- bias (padded table; unconditional bilinear) ----
#pragma unroll
    for (int tn = 0; tn < 4; tn++)
#pragma unroll
      for (int r = 0; r < 4; r++) {
        const int key = 16 * tn + 4 * rg + r;
        const float gyc = qy15 + pos_a[2 * key];
        const float gxc = qx15 + pos_a[2 * key + 1];
        const float y0f = floorf(gyc), x0f = floorf(gxc);
        const float wy = gyc - y0f, wx = gxc - x0f;
        const int iy1 = (int)y0f + 1, ix1 = (int)x0f + 1;
        const float* tp = rpe_f + iy1 * 66 + ix1;
        const float t00 = tp[0], t01 = tp[1];
        const float t10 = tp[66], t11 = tp[67];
        const float r0v = t00 + (t01 - t00) * wx;
        const float r1v = t10 + (t11 - t10) * wx;
        const float bias = r0v + (r1v - r0v) * wy;
        sf[tn][r] = sf[tn][r] * 0.125f + bias;
      }

    // ---- lane-local online softmax over this half's 64-key tile ----
    float tmax = sf[0][0];
#pragma unroll
    for (int tn = 0; tn < 4; tn++)
#pragma unroll
      for (int r = 0; r < 4; r++) tmax = fmaxf(tmax, sf[tn][r]);
    tmax = fmaxf(tmax, __shfl_xor(tmax, 16));
    tmax = fmaxf(tmax, __shfl_xor(tmax, 32));
    const float nmax = fmaxf(rmax, tmax);
    const float corr = __expf(rmax - nmax);
    rmax = nmax;
    float lsum = 0.0f;
    unsigned pw[8];
#pragma unroll
    for (int tn = 0; tn < 4; tn++) {
      const float p0 = __expf(sf[tn][0] - nmax);
      const float p1 = __expf(sf[tn][1] - nmax);
      const float p2 = __expf(sf[tn][2] - nmax);
      const float p3 = __expf(sf[tn][3] - nmax);
      lsum += (p0 + p1) + (p2 + p3);
      pw[2 * tn] = pack2(p0, p1);
      pw[2 * tn + 1] = pack2(p2, p3);
    }
    lsum += __shfl_xor(lsum, 16);
    lsum += __shfl_xor(lsum, 32);
    rsum = rsum * corr + lsum;
#pragma unroll
    for (int tc = 0; tc < 4; tc++) {
      oacc[tc][0] *= corr; oacc[tc][1] *= corr;
      oacc[tc][2] *= corr; oacc[tc][3] *= corr;
    }

    // ---- P^T -> p_lds (wave-private rows; no barrier) ----
#pragma unroll
    for (int tn = 0; tn < 4; tn++) {
      *(unsigned*)(p_base + qloc * 128 + ((2 * (16 * tn + 4 * rg)) ^ swl)) = pw[2 * tn];
      *(unsigned*)(p_base + qloc * 128 + ((2 * (16 * tn + 4 * rg) + 4) ^ swl)) = pw[2 * tn + 1];
    }

    // ---- O^T += V^T · P^T (8 MFMA) ----
#pragma unroll
    for (int kc = 0; kc < 2; kc++) {
      const bf16x8 pb = *(const bf16x8*)(p_base + qloc * 128 + ((2 * (32 * kc + 8 * rg)) ^ swl));
#pragma unroll
      for (int tc = 0; tc < 4; tc++) {
        const int crow = 16 * tc + cl;
        const bf16x8 av = *(const bf16x8*)(v_base + crow * 128 + ((2 * (32 * kc + 8 * rg)) ^ swl));
        oacc[tc] = __builtin_amdgcn_mfma_f32_16x16x32_bf16(av, pb, oacc[tc], 0, 0, 0);
      }
    }
    __syncthreads();
  }

  // ---- combine the two halves' online-softmax states ----
  if (l < 16) {
    m_x[half * 64 + wq * 16 + cl] = rmax;
    s_x[half * 64 + wq * 16 + cl] = rsum;
  }
  __syncthreads();
  const float m0v = m_x[wq * 16 + cl], m1v = m_x[64 + wq * 16 + cl];
  const float s0v = s_x[wq * 16 + cl], s1v = s_x[64 + wq * 16 + cl];
  const float M = fmaxf(m0v, m1v);
  const float f0 = __expf(m0v - M), f1 = __expf(m1v - M);
  const float inv = 1.0f / (f0 * s0v + f1 * s1v);
  const float scale = (half == 0 ? f0 : f1) * inv;
  float* o_st = (float*)smem;  // [64 c][66] f32 (16.9 KB, reuses K region)
  if (half == 0) {
#pragma unroll
    for (int tc = 0; tc < 4; tc++)
#pragma unroll
      for (int r = 0; r < 4; r++)
        o_st[(16 * tc + 4 * rg + r) * 66 + qloc] = oacc[tc][r] * scale;
  }
  __syncthreads();
  if (half == 1) {
#pragma unroll
    for (int tc = 0; tc < 4; tc++)
#pragma unroll
      for (int r = 0; r < 4; r++)
        o_st[(16 * tc + 4 * rg + r) * 66 + qloc] += oacc[tc][r] * scale;
  }
  __syncthreads();
  {
    const int c = t >> 3, mq = (t & 7) * 8;
    unsigned u[4];
#pragma unroll
    for (int i = 0; i < 4; i++)
      u[i] = pack2(o_st[c * 66 + mq + 2 * i], o_st[c * 66 + mq + 2 * i + 1]);
    uint4 outv = {u[0], u[1], u[2], u[3]};
    *(uint4*)(ao + hbase + (size_t)c * 1024 + m0 + mq) = outv;
  }
}

extern "C" void kernel_launch(void* const* d_in, const int* in_sizes, int n_in,
                              void* d_out, int out_size, void* d_ws, size_t ws_size,
                              hipStream_t stream) {
  const float* x    = (const float*)d_in[0];
  const float* w_q  = (const float*)d_in[1];
  const float* b_q  = (const float*)d_in[2];
  const float* w_k  = (const float*)d_in[3];
  const float* b_k  = (const float*)d_in[4];
  const float* w_v  = (const float*)d_in[5];
  const float* b_v  = (const float*)d_in[6];
  const float* w_o  = (const float*)d_in[7];
  const float* b_o  = (const float*)d_in[8];
  const float* dw_w = (const float*)d_in[9];
  const float* dw_b = (const float*)d_in[10];
  const float* ln_g = (const float*)d_in[11];
  const float* ln_b = (const float*)d_in[12];
  const float* off_w= (const float*)d_in[13];
  const float* rpe  = (const float*)d_in[14];

  // Outputs are FLOAT32 (reference returns f32 arrays).
  float* out_y   = (float*)d_out;            // [4,512,32,32]   (2097152 f32)
  float* out_pos = out_y + 2097152;          // [4,4,32,32,2]   (32768 f32)
  float* out_ref = out_pos + 32768;          // [4,4,32,32,2]   (32768 f32)

  // workspace (~18.1 MB): pos f32, then bf16 buffers. x_bf aliases k_ws.
  float* pos_ws = (float*)d_ws;              // 32768 f32
  bf16*  q_ws   = (bf16*)(pos_ws + 32768);   // 2097152 bf16
  bf16*  xs_ws  = q_ws + 2097152;            // 2097152 (reused as ao)
  bf16*  k_ws   = xs_ws + 2097152;           // 2097152 (first used as x_bf)
  bf16*  v_ws   = k_ws + 2097152;            // 2097152
  bf16*  w_bf   = v_ws + 2097152;            // 4*262144 bf16 weights
  bf16*  x_bf   = k_ws;
  bf16*  ao_ws  = xs_ws;

  unsigned short* w_bfu = (unsigned short*)w_bf;

  cvt_kernel<<<dim3(1024, 5), 256, 0, stream>>>(x, w_q, w_k, w_v, w_o,
                                                (unsigned short*)x_bf, w_bfu);
  gemm_kernel<bf16><<<dim3(16, 8, 4), 256, 0, stream>>>(
      w_bfu, b_q, (const unsigned short*)x_bf, q_ws);
  offset_kernel<<<dim3(16, 32), 512, 0, stream>>>(q_ws, dw_w, dw_b, ln_g, ln_b, off_w,
                                                  pos_ws, out_pos, out_ref);
  sample_kernel<<<dim3(16, 128), 256, 0, stream>>>(x, pos_ws, xs_ws);
  gemm_kernel<bf16><<<dim3(16, 8, 4), 256, 0, stream>>>(
      w_bfu + 262144, b_k, (const unsigned short*)xs_ws, k_ws);
  gemm_kernel<bf16><<<dim3(16, 8, 4), 256, 0, stream>>>(
      w_bfu + 2 * 262144, b_v, (const unsigned short*)xs_ws, v_ws);
  attn_kernel<<<dim3(16, 32), 512, 0, stream>>>(q_ws, k_ws, v_ws, pos_ws, rpe, ao_ws);
  gemm_kernel<float><<<dim3(16, 8, 4), 256, 0, stream>>>(
      w_bfu + 3 * 262144, b_o, (const unsigned short*)ao_ws, out_y);
}

// Round 11
// 112.600 us; speedup vs baseline: 14.9623x; 1.0503x over previous
//
#include <hip/hip_runtime.h>
#include <hip/hip_bf16.h>

typedef __hip_bfloat16 bf16;
typedef __attribute__((ext_vector_type(8))) short bf16x8;
typedef __attribute__((ext_vector_type(4))) float f32x4;

#define BDIM 4
#define CDIM 512
#define NHEADS 8
#define NGROUPS 4
#define GCH 128

__device__ __forceinline__ float bf2f(bf16 v) { return __bfloat162float(v); }
__device__ __forceinline__ float bfu2f(unsigned short u) {
  return __uint_as_float(((unsigned)u) << 16);
}
__device__ __forceinline__ unsigned short f2bu(float v) {
  return __hip_bfloat16_raw(__float2bfloat16(v)).x;
}
__device__ __forceinline__ unsigned pack2(float lo, float hi) {
  return (unsigned)f2bu(lo) | ((unsigned)f2bu(hi) << 16);
}

// ---- MFMA GEMM: out_m[b][o][n] = sum_c Wm[o][c]*in[b][c][n] + bias_m[o] ----
// Weights are f32 (converted to bf16 in A-staging, bit-identical to the old
// cvt kernel). IN_F32 selects f32 vs bf16 input. NMAT=2 fuses two weight
// matrices over one shared B staging (K+V gemms).
template <bool IN_F32, typename OutT, int NMAT>
__global__ __launch_bounds__(256) void gemm_kernel(
    const float* __restrict__ W0, const float* __restrict__ bias0,
    const float* __restrict__ W1, const float* __restrict__ bias1,
    const void* __restrict__ in,
    OutT* __restrict__ out0, OutT* __restrict__ out1) {
  __shared__ __align__(16) unsigned char smem[8192 * (NMAT + 1)];
  unsigned char* b_lds = smem + 8192 * NMAT;  // [64 n][64 c] bf16 swz
  const int b = blockIdx.z;
  const int o0 = blockIdx.y * 64;
  const int n0 = blockIdx.x * 64;
  const int t = threadIdx.x, l = t & 63, w = t >> 6;
  const int rg = l >> 4, cl = l & 15;
  const int o_base = (w >> 1) * 32, n_base = (w & 1) * 32;
  const int ao = t >> 2;
  const int ac8 = (t & 3) * 8;
  const int kc2 = (t & 31) * 2;
  const int kn8 = (t >> 5) * 8;
  const unsigned swo = (unsigned)((ao & 7) << 4);
  const float* Ws[2] = {W0, W1};
  const float* Bs[2] = {bias0, bias1};
  OutT* Os[2] = {out0, out1};

  f32x4 acc[NMAT][2][2];
#pragma unroll
  for (int m = 0; m < NMAT; m++)
#pragma unroll
    for (int i = 0; i < 2; i++)
#pragma unroll
      for (int j = 0; j < 2; j++) acc[m][i][j] = {0.f, 0.f, 0.f, 0.f};

  for (int k0 = 0; k0 < 512; k0 += 64) {
    // stage A (f32 weights -> bf16, swizzled)
#pragma unroll
    for (int m = 0; m < NMAT; m++) {
      const float* wr = Ws[m] + (size_t)(o0 + ao) * 512 + k0;
      const float4 a0 = *(const float4*)(wr + ac8);
      const float4 a1 = *(const float4*)(wr + ac8 + 4);
      const float4 c0 = *(const float4*)(wr + ac8 + 32);
      const float4 c1 = *(const float4*)(wr + ac8 + 36);
      uint4 ua = {pack2(a0.x, a0.y), pack2(a0.z, a0.w),
                  pack2(a1.x, a1.y), pack2(a1.z, a1.w)};
      uint4 ub = {pack2(c0.x, c0.y), pack2(c0.z, c0.w),
                  pack2(c1.x, c1.y), pack2(c1.z, c1.w)};
      unsigned char* am = smem + 8192 * m;
      *(uint4*)(am + ao * 128 + ((2 * ac8) ^ swo)) = ua;
      *(uint4*)(am + ao * 128 + ((2 * ac8 + 64) ^ swo)) = ub;
    }
    // stage B (transpose-pack [c][n] -> [n][c], swizzled)
    if constexpr (IN_F32) {
      const float* inb = (const float*)in + (size_t)b * 524288;
      const float* p0 = inb + (size_t)(k0 + kc2) * 1024 + n0 + kn8;
      union { float4 v[2]; float f[8]; } r0, r1;
      r0.v[0] = *(const float4*)p0;
      r0.v[1] = *(const float4*)(p0 + 4);
      r1.v[0] = *(const float4*)(p0 + 1024);
      r1.v[1] = *(const float4*)(p0 + 1028);
#pragma unroll
      for (int i = 0; i < 8; i++) {
        const int n = kn8 + i;
        *(unsigned*)(b_lds + n * 128 + ((2 * kc2) ^ ((n & 7) << 4))) =
            pack2(r0.f[i], r1.f[i]);
      }
    } else {
      const unsigned short* inb = (const unsigned short*)in + (size_t)b * 524288;
      union { uint4 v; unsigned short hw[8]; } r0, r1;
      r0.v = *(const uint4*)(inb + (size_t)(k0 + kc2) * 1024 + n0 + kn8);
      r1.v = *(const uint4*)(inb + (size_t)(k0 + kc2 + 1) * 1024 + n0 + kn8);
#pragma unroll
      for (int i = 0; i < 8; i++) {
        const int n = kn8 + i;
        const unsigned v32 = (unsigned)r0.hw[i] | ((unsigned)r1.hw[i] << 16);
        *(unsigned*)(b_lds + n * 128 + ((2 * kc2) ^ ((n & 7) << 4))) = v32;
      }
    }
    __syncthreads();
#pragma unroll
    for (int kk = 0; kk < 2; kk++) {
      bf16x8 bfr[2];
#pragma unroll
      for (int nn = 0; nn < 2; nn++) {
        const int n_loc = n_base + 16 * nn + cl;
        bfr[nn] = *(const bf16x8*)(b_lds + n_loc * 128 +
                                   ((64 * kk + 16 * rg) ^ ((n_loc & 7) << 4)));
      }
#pragma unroll
      for (int m = 0; m < NMAT; m++) {
        bf16x8 af[2];
#pragma unroll
        for (int mi = 0; mi < 2; mi++) {
          const int o_loc = o_base + 16 * mi + cl;
          af[mi] = *(const bf16x8*)(smem + 8192 * m + o_loc * 128 +
                                    ((64 * kk + 16 * rg) ^ ((o_loc & 7) << 4)));
        }
#pragma unroll
        for (int mi = 0; mi < 2; mi++)
#pragma unroll
          for (int nn = 0; nn < 2; nn++)
            acc[m][mi][nn] = __builtin_amdgcn_mfma_f32_16x16x32_bf16(
                af[mi], bfr[nn], acc[m][mi][nn], 0, 0, 0);
      }
    }
    __syncthreads();
  }

  // epilogue per matrix: stage f32 C tile, coalesced store + bias
  float* o_st = (float*)smem;  // [64][64]
#pragma unroll
  for (int m = 0; m < NMAT; m++) {
    __syncthreads();
#pragma unroll
    for (int mi = 0; mi < 2; mi++)
#pragma unroll
      for (int nn = 0; nn < 2; nn++)
#pragma unroll
        for (int r = 0; r < 4; r++)
          o_st[(o_base + 16 * mi + 4 * rg + r) * 64 + n_base + 16 * nn + cl] =
              acc[m][mi][nn][r];
    __syncthreads();
    const int eo = t >> 4;
    const int en = (t & 15) * 4;
#pragma unroll
    for (int pass = 0; pass < 4; pass++) {
      const int o_loc = eo + pass * 16;
      const f32x4 v = *(const f32x4*)(o_st + o_loc * 64 + en);
      const float bv = Bs[m][o0 + o_loc];
      if constexpr (sizeof(OutT) == 2) {
        ushort4 u;
        u.x = f2bu(v[0] + bv);
        u.y = f2bu(v[1] + bv);
        u.z = f2bu(v[2] + bv);
        u.w = f2bu(v[3] + bv);
        *(ushort4*)((bf16*)Os[m] + ((size_t)b * 512 + o0 + o_loc) * 1024 + n0 + en) = u;
      } else {
        float4 r = {v[0] + bv, v[1] + bv, v[2] + bv, v[3] + bv};
        *(float4*)((float*)Os[m] + ((size_t)b * 512 + o0 + o_loc) * 1024 + n0 + en) = r;
      }
    }
  }
}

// depthwise 5x5 conv + LayerNorm(128) + GELU + 1x1(128->2) + tanh -> pos.
// (round-9 restructure; verified)
__global__ __launch_bounds__(512) void offset_kernel(
    const bf16* __restrict__ q, const float* __restrict__ dw_w,
    const float* __restrict__ dw_b, const float* __restrict__ ln_g,
    const float* __restrict__ ln_b, const float* __restrict__ off_w,
    float* __restrict__ pos, float* __restrict__ out_pos, float* __restrict__ out_ref) {
  __shared__ unsigned short q_s[5][36][128];  // 46080 B
  __shared__ float red_a[4][2][2];
  __shared__ float red_p[4][2][2];
  const int bg = blockIdx.x;
  const int h = blockIdx.y;
  const int b = bg >> 2, g = bg & 3;
  const int t = threadIdx.x;

  for (int task = t; task < 640; task += 512) {
    const int ky = task >> 7, c = task & 127;
    const int y = h + ky - 2;
    if (y >= 0 && y < 32) {
      const unsigned short* qrow =
          (const unsigned short*)q + ((size_t)b * CDIM + g * GCH + c) * 1024 + y * 32;
      q_s[ky][0][c] = 0;
      q_s[ky][1][c] = 0;
#pragma unroll
      for (int x8 = 0; x8 < 4; x8++) {
        union { uint4 u; unsigned short s[8]; } vv;
        vv.u = *(const uint4*)(qrow + x8 * 8);
#pragma unroll
        for (int i = 0; i < 8; i++) q_s[ky][2 + x8 * 8 + i][c] = vv.s[i];
      }
      q_s[ky][34][c] = 0;
      q_s[ky][35][c] = 0;
    } else {
#pragma unroll
      for (int xi = 0; xi < 36; xi++) q_s[ky][xi][c] = 0;
    }
  }

  const int wslot = t >> 7;
  const int c = t & 127;
  const int half = c >> 6;
  const int lane = t & 63;
  float wgt[25];
#pragma unroll
  for (int i = 0; i < 25; i++) wgt[i] = dw_w[c * 25 + i];
  const float cbias = dw_b[c];
  const float gam = ln_g[c], bet = ln_b[c];
  const float ow0 = off_w[c], ow1 = off_w[GCH + c];
  __syncthreads();

  for (int j = 0; j < 8; j++) {
    const int w = wslot * 8 + j;
    float s = cbias;
#pragma unroll
    for (int ky = 0; ky < 5; ky++)
#pragma unroll
      for (int kx = 0; kx < 5; kx++)
        s += wgt[ky * 5 + kx] * bfu2f(q_s[ky][w + kx][c]);
    float ssum = s, ssq = s * s;
#pragma unroll
    for (int o = 1; o < 64; o <<= 1) {
      ssum += __shfl_xor(ssum, o);
      ssq += __shfl_xor(ssq, o);
    }
    if (lane == 0) { red_a[wslot][half][0] = ssum; red_a[wslot][half][1] = ssq; }
    __syncthreads();
    const float mu = (red_a[wslot][0][0] + red_a[wslot][1][0]) * (1.0f / 128.0f);
    const float var = (red_a[wslot][0][1] + red_a[wslot][1][1]) * (1.0f / 128.0f) - mu * mu;
    const float xn = (s - mu) * rsqrtf(var + 1e-5f) * gam + bet;
    const float ge = 0.5f * xn * (1.0f + erff(xn * 0.70710678118654752f));
    float p0 = ow0 * ge, p1 = ow1 * ge;
#pragma unroll
    for (int o = 1; o < 64; o <<= 1) {
      p0 += __shfl_xor(p0, o);
      p1 += __shfl_xor(p1, o);
    }
    if (lane == 0) { red_p[wslot][half][0] = p0; red_p[wslot][half][1] = p1; }
    __syncthreads();
    if (c == 0) {
      const float oy = tanhf(red_p[wslot][0][0] + red_p[wslot][1][0]) * 0.0625f;
      const float ox = tanhf(red_p[wslot][0][1] + red_p[wslot][1][1]) * 0.0625f;
      const float ry = ((float)h + 0.5f) * (2.0f / 32.0f) - 1.0f;
      const float rx = ((float)w + 0.5f) * (2.0f / 32.0f) - 1.0f;
      const float py = oy + ry, px = ox + rx;
      const size_t idx = (size_t)bg * 1024 + h * 32 + w;
      pos[idx * 2] = py;
      pos[idx * 2 + 1] = px;
      out_pos[idx * 2] = py;
      out_pos[idx * 2 + 1] = px;
      out_ref[idx * 2] = ry;
      out_ref[idx * 2 + 1] = rx;
    }
  }
}

// bilinear grid-sample of x at pos -> xs [16][128][1024]
__global__ __launch_bounds__(256) void sample_kernel(
    const float* __restrict__ x, const float* __restrict__ pos, bf16* __restrict__ xs) {
  const int bg = blockIdx.x, c = blockIdx.y;
  const int b = bg >> 2, g = bg & 3;
  __shared__ float plane[1024];
  const float* xp = x + ((size_t)b * CDIM + g * GCH + c) * 1024;
  for (int i = threadIdx.x; i < 1024; i += 256) plane[i] = xp[i];
  __syncthreads();
  for (int s = threadIdx.x; s < 1024; s += 256) {
    const float py = pos[((size_t)bg * 1024 + s) * 2];
    const float px = pos[((size_t)bg * 1024 + s) * 2 + 1];
    const float gx = (px + 1.0f) * 15.5f;
    const float gy = (py + 1.0f) * 15.5f;
    const float x0f = floorf(gx), y0f = floorf(gy);
    const float wx = gx - x0f, wy = gy - y0f;
    const int ix = (int)x0f, iy = (int)y0f;
    float r = 0.0f;
    const bool vx0 = (ix >= 0) & (ix <= 31), vx1 = (ix + 1 >= 0) & (ix + 1 <= 31);
    const bool vy0 = (iy >= 0) & (iy <= 31), vy1 = (iy + 1 >= 0) & (iy + 1 <= 31);
    if (vy0 && vx0) r += plane[iy * 32 + ix] * (1.0f - wx) * (1.0f - wy);
    if (vy0 && vx1) r += plane[iy * 32 + ix + 1] * wx * (1.0f - wy);
    if (vy1 && vx0) r += plane[(iy + 1) * 32 + ix] * (1.0f - wx) * wy;
    if (vy1 && vx1) r += plane[(iy + 1) * 32 + ix + 1] * wx * wy;
    xs[((size_t)bg * GCH + c) * 1024 + s] = __float2bfloat16(r);
  }
}

// Swapped-operand MFMA attention, split-KV x2, P-overlays-K.
// LDS 50.8 KB -> 3 blocks/CU (24 waves/CU). P shares the K region (K dead
// after QK); one barrier between QK-reads and P-writes guards the overlay.
// PV reads only the lane's own query row of P (wave-private) -> no more sync.
__global__ __launch_bounds__(512) void attn_kernel(
    const bf16* __restrict__ q, const bf16* __restrict__ kk,
    const bf16* __restrict__ vv, const float* __restrict__ pos,
    const float* __restrict__ rpe, bf16* __restrict__ ao) {
  __shared__ __align__(16) unsigned char smem[51976];
  // [0,16384): K tiles (half*8192), overlaid by P after QK
  // [16384,32768): V | [32768,49928): rpe_f [65][66] f32
  // [49928,50952): pos_a [2][128] | [50952,51464): m_x | [51464,51976): s_x
  float* rpe_f = (float*)(smem + 32768);
  float* m_x = (float*)(smem + 50952);
  float* s_x = (float*)(smem + 51464);

  const int bh = blockIdx.y;
  const int m0 = blockIdx.x * 64;
  const int b = bh >> 3, h = bh & 7;
  const int g = h >> 1;
  const int bg = b * 4 + g;
  const int t = threadIdx.x, l = t & 63, w = t >> 6;
  const int wq = w & 3, half = w >> 2;
  const int rg = l >> 4, cl = l & 15;
  const int t2 = t & 255;
  const size_t hbase = ((size_t)b * CDIM + h * 64) * 1024;
  const unsigned short* qu = (const unsigned short*)q;

  unsigned char* k_base = smem + half * 8192;           // K, then P
  unsigned char* v_base = smem + 16384 + half * 8192;
  float* pos_a = (float*)(smem + 49928) + half * 128;

  for (int i = t; i < 65 * 66; i += 512) {
    const int y = i / 66, x = i - y * 66;
    float v = 0.0f;
    if (y >= 1 && y <= 63 && x >= 1 && x <= 63)
      v = rpe[h * 3969 + (y - 1) * 63 + (x - 1)];
    rpe_f[i] = v;
  }

  const int qloc = 16 * wq + cl;
  const int qm = m0 + qloc;
  const float qy15 = 15.5f * (((float)(qm >> 5) + 0.5f) * (2.0f / 32.0f) - 1.0f);
  const float qx15 = 15.5f * (((float)(qm & 31) + 0.5f) * (2.0f / 32.0f) - 1.0f);

  bf16x8 bq[2];
#pragma unroll
  for (int kc = 0; kc < 2; kc++) {
    bf16x8 a;
#pragma unroll
    for (int j = 0; j < 8; j++)
      a[j] = (short)qu[hbase + (size_t)(32 * kc + 8 * rg + j) * 1024 + qm];
    bq[kc] = a;
  }

  float rmax = -1e30f, rsum = 0.0f;
  f32x4 oacc[4] = {{0.f,0.f,0.f,0.f},{0.f,0.f,0.f,0.f},
                   {0.f,0.f,0.f,0.f},{0.f,0.f,0.f,0.f}};

  const float* posb = pos + (size_t)bg * 2048;
  const unsigned swl = (unsigned)((cl & 7) << 4);
  const int kc2 = (t2 & 31) * 2;
  const int kn8 = (t2 >> 5) * 8;
  const int vc = t2 >> 2;
  const int vh = (t2 & 3) * 32;

  for (int tile = 0; tile < 8; tile++) {
    const int n0 = half * 512 + tile * 64;
    // ---- stage K (transpose-pack) + V + pos ----
    {
      union { uint4 v; unsigned short hw[8]; } r0, r1;
      r0.v = *(const uint4*)(kk + hbase + (size_t)kc2 * 1024 + n0 + kn8);
      r1.v = *(const uint4*)(kk + hbase + (size_t)(kc2 + 1) * 1024 + n0 + kn8);
#pragma unroll
      for (int i = 0; i < 8; i++) {
        const int n = kn8 + i;
        const unsigned v32 = (unsigned)r0.hw[i] | ((unsigned)r1.hw[i] << 16);
        *(unsigned*)(k_base + n * 128 + ((kc2 * 2) ^ ((n & 7) << 4))) = v32;
      }
      const uint4 s0 = *(const uint4*)(vv + hbase + (size_t)vc * 1024 + n0 + vh / 2);
      const uint4 s1 = *(const uint4*)(vv + hbase + (size_t)vc * 1024 + n0 + vh / 2 + 8);
      *(uint4*)(v_base + vc * 128 + (vh ^ ((vc & 7) << 4))) = s0;
      *(uint4*)(v_base + vc * 128 + ((vh + 16) ^ ((vc & 7) << 4))) = s1;
      if (t2 < 128) pos_a[t2] = 31.0f - 15.5f * posb[2 * n0 + t2];
    }
    __syncthreads();  // staged K/V/pos visible

    // ---- S^T = K·Q (8 MFMA) ----
    f32x4 sf[4];
#pragma unroll
    for (int tn = 0; tn < 4; tn++) {
      const int nrow = 16 * tn + cl;
      const bf16x8 a0 = *(const bf16x8*)(k_base + nrow * 128 + ((16 * rg) ^ swl));
      const bf16x8 a1 = *(const bf16x8*)(k_base + nrow * 128 + ((64 + 16 * rg) ^ swl));
      f32x4 z = {0.f, 0.f, 0.f, 0.f};
      z = __builtin_amdgcn_mfma_f32_16x16x32_bf16(a0, bq[0], z, 0, 0, 0);
      z = __builtin_amdgcn_mfma_f32_16x16x32_bf16(a1, bq[1], z, 0, 0, 0);
      sf[tn] = z;
    }

    // ---- bias (padded table; unconditional bilinear) ----
#pragma unroll
    for (int tn = 0; tn < 4; tn++)
#pragma unroll
      for (int r = 0; r < 4; r++) {
        const int key = 16 * tn + 4 * rg + r;
        const float gyc = qy15 + pos_a[2 * key];
        const float gxc = qx15 + pos_a[2 * key + 1];
        const float y0f = floorf(gyc), x0f = floorf(gxc);
        const float wy = gyc - y0f, wx = gxc - x0f;
        const int iy1 = (int)y0f + 1, ix1 = (int)x0f + 1;
        const float* tp = rpe_f + iy1 * 66 + ix1;
        const float t00 = tp[0], t01 = tp[1];
        const float t10 = tp[66], t11 = tp[67];
        const float r0v = t00 + (t01 - t00) * wx;
        const float r1v = t10 + (t11 - t10) * wx;
        const float bias = r0v + (r1v - r0v) * wy;
        sf[tn][r] = sf[tn][r] * 0.125f + bias;
      }

    // ---- lane-local online softmax ----
    float tmax = sf[0][0];
#pragma unroll
    for (int tn = 0; tn < 4; tn++)
#pragma unroll
      for (int r = 0; r < 4; r++) tmax = fmaxf(tmax, sf[tn][r]);
    tmax = fmaxf(tmax, __shfl_xor(tmax, 16));
    tmax = fmaxf(tmax, __shfl_xor(tmax, 32));
    const float nmax = fmaxf(rmax, tmax);
    const float corr = __expf(rmax - nmax);
    rmax = nmax;
    float lsum = 0.0f;
    unsigned pw[8];
#pragma unroll
    for (int tn = 0; tn < 4; tn++) {
      const float p0 = __expf(sf[tn][0] - nmax);
      const float p1 = __expf(sf[tn][1] - nmax);
      const float p2 = __expf(sf[tn][2] - nmax);
      const float p3 = __expf(sf[tn][3] - nmax);
      lsum += (p0 + p1) + (p2 + p3);
      pw[2 * tn] = pack2(p0, p1);
      pw[2 * tn + 1] = pack2(p2, p3);
    }
    lsum += __shfl_xor(lsum, 16);
    lsum += __shfl_xor(lsum, 32);
    rsum = rsum * corr + lsum;
#pragma unroll
    for (int tc = 0; tc < 4; tc++) {
      oacc[tc][0] *= corr; oacc[tc][1] *= corr;
      oacc[tc][2] *= corr; oacc[tc][3] *= corr;
    }

    __syncthreads();  // all waves' QK reads of k_base complete before P overlay

    // ---- P^T -> k_base region (wave-private rows) ----
#pragma unroll
    for (int tn = 0; tn < 4; tn++) {
      *(unsigned*)(k_base + qloc * 128 + ((2 * (16 * tn + 4 * rg)) ^ swl)) = pw[2 * tn];
      *(unsigned*)(k_base + qloc * 128 + ((2 * (16 * tn + 4 * rg) + 4) ^ swl)) = pw[2 * tn + 1];
    }

    // ---- O^T += V^T · P^T (8 MFMA) ----
#pragma unroll
    for (int kc = 0; kc < 2; kc++) {
      const bf16x8 pb = *(const bf16x8*)(k_base + qloc * 128 + ((2 * (32 * kc + 8 * rg)) ^ swl));
#pragma unroll
      for (int tc = 0; tc < 4; tc++) {
        const int crow = 16 * tc + cl;
        const bf16x8 av = *(const bf16x8*)(v_base + crow * 128 + ((2 * (32 * kc + 8 * rg)) ^ swl));
        oacc[tc] = __builtin_amdgcn_mfma_f32_16x16x32_bf16(av, pb, oacc[tc], 0, 0, 0);
      }
    }
    __syncthreads();  // P/V reads done before next stage overwrites
  }

  // ---- combine the two halves' online-softmax states ----
  if (l < 16) {
    m_x[half * 64 + wq * 16 + cl] = rmax;
    s_x[half * 64 + wq * 16 + cl] = rsum;
  }
  __syncthreads();
  const float m0v = m_x[wq * 16 + cl], m1v = m_x[64 + wq * 16 + cl];
  const float s0v = s_x[wq * 16 + cl], s1v = s_x[64 + wq * 16 + cl];
  const float M = fmaxf(m0v, m1v);
  const float f0 = __expf(m0v - M), f1 = __expf(m1v - M);
  const float inv = 1.0f / (f0 * s0v + f1 * s1v);
  const float scale = (half == 0 ? f0 : f1) * inv;
  float* o_st = (float*)smem;  // [64 c][66] f32 (16.9 KB; K/P + V-head reuse)
  if (half == 0) {
#pragma unroll
    for (int tc = 0; tc < 4; tc++)
#pragma unroll
      for (int r = 0; r < 4; r++)
        o_st[(16 * tc + 4 * rg + r) * 66 + qloc] = oacc[tc][r] * scale;
  }
  __syncthreads();
  if (half == 1) {
#pragma unroll
    for (int tc = 0; tc < 4; tc++)
#pragma unroll
      for (int r = 0; r < 4; r++)
        o_st[(16 * tc + 4 * rg + r) * 66 + qloc] += oacc[tc][r] * scale;
  }
  __syncthreads();
  {
    const int c = t >> 3, mq = (t & 7) * 8;
    unsigned u[4];
#pragma unroll
    for (int i = 0; i < 4; i++)
      u[i] = pack2(o_st[c * 66 + mq + 2 * i], o_st[c * 66 + mq + 2 * i + 1]);
    uint4 outv = {u[0], u[1], u[2], u[3]};
    *(uint4*)(ao + hbase + (size_t)c * 1024 + m0 + mq) = outv;
  }
}

extern "C" void kernel_launch(void* const* d_in, const int* in_sizes, int n_in,
                              void* d_out, int out_size, void* d_ws, size_t ws_size,
                              hipStream_t stream) {
  const float* x    = (const float*)d_in[0];
  const float* w_q  = (const float*)d_in[1];
  const float* b_q  = (const float*)d_in[2];
  const float* w_k  = (const float*)d_in[3];
  const float* b_k  = (const float*)d_in[4];
  const float* w_v  = (const float*)d_in[5];
  const float* b_v  = (const float*)d_in[6];
  const float* w_o  = (const float*)d_in[7];
  const float* b_o  = (const float*)d_in[8];
  const float* dw_w = (const float*)d_in[9];
  const float* dw_b = (const float*)d_in[10];
  const float* ln_g = (const float*)d_in[11];
  const float* ln_b = (const float*)d_in[12];
  const float* off_w= (const float*)d_in[13];
  const float* rpe  = (const float*)d_in[14];

  // Outputs are FLOAT32 (reference returns f32 arrays).
  float* out_y   = (float*)d_out;            // [4,512,32,32]   (2097152 f32)
  float* out_pos = out_y + 2097152;          // [4,4,32,32,2]   (32768 f32)
  float* out_ref = out_pos + 32768;          // [4,4,32,32,2]   (32768 f32)

  // workspace (~16.1 MB): pos f32, then bf16 buffers.
  float* pos_ws = (float*)d_ws;              // 32768 f32
  bf16*  q_ws   = (bf16*)(pos_ws + 32768);   // 2097152 bf16
  bf16*  xs_ws  = q_ws + 2097152;            // 2097152 (reused as ao)
  bf16*  k_ws   = xs_ws + 2097152;           // 2097152
  bf16*  v_ws   = k_ws + 2097152;            // 2097152
  bf16*  ao_ws  = xs_ws;                     // xs dead after k/v gemm

  gemm_kernel<true, bf16, 1><<<dim3(16, 8, 4), 256, 0, stream>>>(
      w_q, b_q, nullptr, nullptr, x, q_ws, (bf16*)nullptr);
  offset_kernel<<<dim3(16, 32), 512, 0, stream>>>(q_ws, dw_w, dw_b, ln_g, ln_b, off_w,
                                                  pos_ws, out_pos, out_ref);
  sample_kernel<<<dim3(16, 128), 256, 0, stream>>>(x, pos_ws, xs_ws);
  gemm_kernel<false, bf16, 2><<<dim3(16, 8, 4), 256, 0, stream>>>(
      w_k, b_k, w_v, b_v, xs_ws, k_ws, v_ws);
  attn_kernel<<<dim3(16, 32), 512, 0, stream>>>(q_ws, k_ws, v_ws, pos_ws, rpe, ao_ws);
  gemm_kernel<false, float, 1><<<dim3(16, 8, 4), 256, 0, stream>>>(
      w_o, b_o, nullptr, nullptr, ao_ws, out_y, (float*)nullptr);
}